// Round 1
// baseline (9721.441 us; speedup 1.0000x reference)
//
#include <hip/hip_runtime.h>
#include <hip/hip_bf16.h>

#define NS    32768    // samples
#define NA    1024     // atoms
#define AL    2048     // atom length
#define KKEEP 1024     // top-k
#define CAPC  (512*1024)

struct Cand { float v; unsigned idx; };

// ---------------------------------------------------------------------------
// ws layout (bytes):
//   0      : float hdr[3]      = { sumsq x[b=0], sumsq x[b=1], sumsq atoms }
//   16     : unsigned candCnt[2]
//   64     : Cand sel[2][KKEEP]        (16 KB)
//   65536  : Cand cand[2][cap]         (cap*16 bytes total)
// ---------------------------------------------------------------------------

__global__ void sums_kernel(const float* __restrict__ x, const float* __restrict__ atoms,
                            float* __restrict__ hdr) {
    const long total = 2L*NS + (long)NA*AL;
    float sx0 = 0.f, sx1 = 0.f, sa = 0.f;
    for (long i = (long)blockIdx.x*blockDim.x + threadIdx.x; i < total;
         i += (long)gridDim.x*blockDim.x) {
        if (i < NS)        { float v = x[i];           sx0 += v*v; }
        else if (i < 2*NS) { float v = x[i];           sx1 += v*v; }
        else               { float v = atoms[i - 2*NS]; sa += v*v; }
    }
    #pragma unroll
    for (int o = 32; o >= 1; o >>= 1) {
        sx0 += __shfl_down(sx0, o);
        sx1 += __shfl_down(sx1, o);
        sa  += __shfl_down(sa , o);
    }
    if ((threadIdx.x & 63) == 0) {
        if (sx0 != 0.f) atomicAdd(&hdr[0], sx0);
        if (sx1 != 0.f) atomicAdd(&hdr[1], sx1);
        if (sa  != 0.f) atomicAdd(&hdr[2], sa);
    }
}

// ---------------------------------------------------------------------------
// fm[b,a,t] = sum_{k=0}^{AL-1} atoms[a,k] * x[b, t-k]   (t-k >= 0)
// Tiled implicit GEMM: BM=128 atoms x BN=128 t per block, K-chunks of 64.
// Appends (v, a*NS+t) for v > T0 = 3*sigma into per-batch candidate buffers.
// ---------------------------------------------------------------------------
#define BM  128
#define BN  128
#define BKC 64
#define LDA 68   // padded LDS stride for atom tile (bank-conflict-free reads)

__global__ __launch_bounds__(256, 4)
void fm_kernel(const float* __restrict__ x, const float* __restrict__ atoms,
               const float* __restrict__ hdr, unsigned* __restrict__ candCnt,
               Cand* __restrict__ cand, unsigned cap) {
    __shared__ float sA[BM * LDA];     // 34816 B
    __shared__ float sX[BN + BKC];     // 192 floats

    const int bid = blockIdx.x;
    const int b   = bid >> 11;         // grid = 2 * 8 * 256
    const int rem = bid & 2047;
    const int aT  = rem >> 8;          // 0..7
    const int tT  = rem & 255;         // 0..255
    const int a0  = aT * BM;
    const int t0  = tT * BN;

    const int tid = threadIdx.x;
    const int ta  = tid >> 4;          // 0..15
    const int tt  = tid & 15;          // 0..15

    const float* __restrict__ xb = x + b * NS;

    float acc[8][8];
    #pragma unroll
    for (int i = 0; i < 8; ++i)
        #pragma unroll
        for (int j = 0; j < 8; ++j) acc[i][j] = 0.f;

    for (int kc = 0; kc < AL; kc += BKC) {
        __syncthreads();
        // stage atom chunk: atoms[a0+al][kc+kf..kf+3] -> sA[al*LDA+kf]
        #pragma unroll
        for (int it = 0; it < 8; ++it) {
            int flat = it * 256 + tid;           // 0..2047
            int al   = flat >> 4;                // 0..127
            int kf   = (flat & 15) << 2;         // 0..60
            float4 g = *(const float4*)(atoms + (size_t)(a0 + al) * AL + kc + kf);
            *(float4*)(sA + al * LDA + kf) = g;
        }
        // stage x window: indices [t0-kc-63, t0-kc+128]
        if (tid < BN + BKC) {
            int xi = t0 - kc - 63 + tid;
            sX[tid] = (xi >= 0 && xi < NS) ? xb[xi] : 0.f;
        }
        __syncthreads();

        #pragma unroll 4
        for (int kk = 0; kk < BKC; ++kk) {
            float xv[8], av[8];
            #pragma unroll
            for (int j = 0; j < 8; ++j) xv[j] = sX[tt + 16 * j + 63 - kk];
            #pragma unroll
            for (int i = 0; i < 8; ++i) av[i] = sA[(ta + 16 * i) * LDA + kk];
            #pragma unroll
            for (int i = 0; i < 8; ++i)
                #pragma unroll
                for (int j = 0; j < 8; ++j) acc[i][j] += av[i] * xv[j];
        }
    }

    // threshold = 3 * sqrt(mean||atom||^2 * var(x_b)); candidates are ~45k/batch,
    // cutoff (rank-1024) sits at ~4 sigma -> huge safety margin.
    const float sig = sqrtf((hdr[2] * (1.0f / (float)NA)) * (hdr[b] * (1.0f / (float)NS)));
    const float T0  = 3.0f * sig;

    #pragma unroll
    for (int i = 0; i < 8; ++i) {
        #pragma unroll
        for (int j = 0; j < 8; ++j) {
            float v = acc[i][j];
            if (v > T0) {
                unsigned a   = (unsigned)(a0 + ta + 16 * i);
                unsigned t   = (unsigned)(t0 + tt + 16 * j);
                unsigned idx = (a << 15) | t;
                unsigned pos = atomicAdd(&candCnt[b], 1u);
                if (pos < cap) {
                    Cand c; c.v = v; c.idx = idx;
                    cand[(size_t)b * cap + pos] = c;
                }
            }
        }
    }
}

// ---------------------------------------------------------------------------
// Recompute each candidate's fm value exactly (fp64 accumulation).
// One wave per candidate. Makes selection ranking exact regardless of the
// fm kernel's precision.
// ---------------------------------------------------------------------------
__global__ void refine_kernel(const float* __restrict__ x, const float* __restrict__ atoms,
                              const unsigned* __restrict__ candCnt, Cand* __restrict__ cand,
                              unsigned cap) {
    const int lane = threadIdx.x & 63;
    const int wid  = (int)((blockIdx.x * blockDim.x + threadIdx.x) >> 6);
    const int nw   = (int)((gridDim.x * blockDim.x) >> 6);
    const int n0 = (int)min(candCnt[0], cap);
    const int n1 = (int)min(candCnt[1], cap);
    const int total = n0 + n1;
    for (int c = wid; c < total; c += nw) {
        const int b = (c < n0) ? 0 : 1;
        const size_t ci = (c < n0) ? (size_t)c : ((size_t)cap + (size_t)(c - n0));
        const unsigned idx = cand[ci].idx;
        const int a = (int)(idx >> 15);
        const int t = (int)(idx & (NS - 1));
        const float* __restrict__ ar = atoms + (size_t)a * AL;
        const float* __restrict__ xr = x + b * NS;
        double s = 0.0;
        for (int k = lane; k < AL; k += 64) {
            int xi = t - k;
            if (xi >= 0) s += (double)ar[k] * (double)xr[xi];
        }
        #pragma unroll
        for (int o = 32; o >= 1; o >>= 1) s += __shfl_down(s, o);
        if (lane == 0) cand[ci].v = (float)s;
    }
}

// ---------------------------------------------------------------------------
// Exact top-KKEEP per batch among candidates: binary search on the threshold,
// ties broken by ascending flat index (jax.lax.top_k semantics).
// One block (1024 threads) per batch.
// ---------------------------------------------------------------------------
__global__ void select_kernel(const unsigned* __restrict__ candCnt,
                              const Cand* __restrict__ cand, Cand* __restrict__ sel,
                              unsigned cap) {
    __shared__ float    s_red[16];
    __shared__ int      s_cnt;
    __shared__ int      s_nA;
    __shared__ int      s_nT;
    __shared__ int      s_exact;
    __shared__ float    s_tau;
    __shared__ Cand     s_A[KKEEP];
    __shared__ unsigned s_T[256];

    const int b = blockIdx.x;
    const Cand* __restrict__ cb = cand + (size_t)b * cap;
    const int n   = (int)min(candCnt[b], cap);
    const int tid = threadIdx.x;

    if (n <= KKEEP) {   // unreachable statistically; safe fallback
        for (int i = tid; i < KKEEP; i += blockDim.x) {
            Cand z; z.v = 0.f; z.idx = 0u;
            sel[b * KKEEP + i] = (i < n) ? cb[i] : z;
        }
        return;
    }

    // max reduce (all candidate values are > T0 > 0)
    float m = 0.f;
    for (int i = tid; i < n; i += blockDim.x) m = fmaxf(m, cb[i].v);
    #pragma unroll
    for (int o = 32; o >= 1; o >>= 1) m = fmaxf(m, __shfl_down(m, o));
    if ((tid & 63) == 0) s_red[tid >> 6] = m;
    if (tid == 0) s_exact = 0;
    __syncthreads();
    float hi;
    {
        float mm = 0.f;
        #pragma unroll
        for (int w = 0; w < 16; ++w) mm = fmaxf(mm, s_red[w]);
        hi = mm;
    }
    float lo = 0.f;
    // invariant: count(>lo) >= K > count(>hi)
    for (int iter = 0; iter < 64; ++iter) {
        float mid = 0.5f * (lo + hi);
        if (!(mid > lo && mid < hi)) break;   // float-adjacent: done
        if (tid == 0) s_cnt = 0;
        __syncthreads();
        int c = 0;
        for (int i = tid; i < n; i += blockDim.x) c += (cb[i].v > mid) ? 1 : 0;
        #pragma unroll
        for (int o = 32; o >= 1; o >>= 1) c += __shfl_down(c, o);
        if ((tid & 63) == 0) atomicAdd(&s_cnt, c);
        __syncthreads();
        int cm = s_cnt;
        __syncthreads();
        if (cm == KKEEP) { if (tid == 0) { s_tau = mid; s_exact = 1; } break; }
        if (cm > KKEEP) lo = mid; else hi = mid;
    }
    __syncthreads();

    const int   exact = s_exact;
    const float tau   = exact ? s_tau : hi;   // non-exact: ties all equal `hi` exactly

    for (int i = tid; i < KKEEP; i += blockDim.x) { s_A[i].v = 0.f; s_A[i].idx = 0u; }
    if (tid == 0) { s_nA = 0; s_nT = 0; }
    __syncthreads();

    for (int i = tid; i < n; i += blockDim.x) {
        float v = cb[i].v;
        if (v > tau) {
            int p = atomicAdd(&s_nA, 1);
            if (p < KKEEP) s_A[p] = cb[i];
        } else if (!exact && v == tau) {
            int p = atomicAdd(&s_nT, 1);
            if (p < 256) s_T[p] = cb[i].idx;
        }
    }
    __syncthreads();
    if (tid == 0) {
        int nA = s_nA; if (nA > KKEEP) nA = KKEEP;
        int need = KKEEP - nA;
        int nT = s_nT; if (nT > 256) nT = 256;
        for (int r = 0; r < need && r < nT; ++r) {   // ties: ascending index
            unsigned best = 0xffffffffu; int bj = -1;
            for (int j = 0; j < nT; ++j) if (s_T[j] < best) { best = s_T[j]; bj = j; }
            Cand c; c.v = tau; c.idx = best;
            s_A[nA + r] = c;
            if (bj >= 0) s_T[bj] = 0xffffffffu;
        }
    }
    __syncthreads();
    for (int i = tid; i < KKEEP; i += blockDim.x) sel[b * KKEEP + i] = s_A[i];
}

// ---------------------------------------------------------------------------
// recon[b,t] = sum over kept entries e: val_e * atoms[a_e, t - t0_e]
// Gather form: one thread per output sample; deterministic fp32 sum.
// ---------------------------------------------------------------------------
__global__ void recon_kernel(const float* __restrict__ atoms, const Cand* __restrict__ sel,
                             float* __restrict__ out) {
    __shared__ float          s_v[KKEEP];
    __shared__ unsigned short s_a[KKEEP];
    __shared__ unsigned short s_t[KKEEP];
    const int b = blockIdx.x >> 7;                       // 128 blocks per batch
    const int t = ((blockIdx.x & 127) << 8) + threadIdx.x;
    for (int i = threadIdx.x; i < KKEEP; i += blockDim.x) {
        Cand c = sel[b * KKEEP + i];
        s_v[i] = c.v;
        s_a[i] = (unsigned short)(c.idx >> 15);
        s_t[i] = (unsigned short)(c.idx & (NS - 1));
    }
    __syncthreads();
    float acc = 0.f;
    for (int e = 0; e < KKEEP; ++e) {
        int d = t - (int)s_t[e];
        if ((unsigned)d < (unsigned)AL)
            acc += s_v[e] * atoms[(size_t)s_a[e] * AL + d];
    }
    out[b * NS + t] = acc;
}

extern "C" void kernel_launch(void* const* d_in, const int* in_sizes, int n_in,
                              void* d_out, int out_size, void* d_ws, size_t ws_size,
                              hipStream_t stream) {
    const float* x     = (const float*)d_in[0];   // (2,1,32768)
    const float* atoms = (const float*)d_in[1];   // (1,1024,2048)
    float* out = (float*)d_out;                   // (2,1,32768)

    float*    hdr     = (float*)d_ws;
    unsigned* candCnt = (unsigned*)((char*)d_ws + 16);
    Cand*     sel     = (Cand*)((char*)d_ws + 64);
    Cand*     cand    = (Cand*)((char*)d_ws + 65536);

    // candidate capacity per batch, bounded by available workspace
    unsigned cap = CAPC;
    if (ws_size > 65536 + 2 * sizeof(Cand) * 1024) {
        size_t fit = (ws_size - 65536) / (2 * sizeof(Cand));
        if (fit < cap) cap = (unsigned)fit;
    } else {
        cap = 1024;
    }

    hipMemsetAsync(d_ws, 0, 256, stream);  // hdr + counters
    sums_kernel  <<<512, 256, 0, stream>>>(x, atoms, hdr);
    fm_kernel    <<<2 * (NA / BM) * (NS / BN), 256, 0, stream>>>(x, atoms, hdr, candCnt, cand, cap);
    refine_kernel<<<2048, 256, 0, stream>>>(x, atoms, candCnt, cand, cap);
    select_kernel<<<2, 1024, 0, stream>>>(candCnt, cand, sel, cap);
    recon_kernel <<<256, 256, 0, stream>>>(atoms, sel, out);
}

// Round 3
// 1372.763 us; speedup vs baseline: 7.0817x; 7.0817x over previous
//
#include <hip/hip_runtime.h>
#include <hip/hip_bf16.h>

#define NS    32768    // samples
#define NA    1024     // atoms
#define AL    2048     // atom length
#define KKEEP 1024     // top-k
#define CAPC  (512*1024)

struct Cand { float v; unsigned idx; };

typedef short  short8 __attribute__((ext_vector_type(8)));
typedef float  f32x4  __attribute__((ext_vector_type(4)));

// ---------------------------------------------------------------------------
// ws layout (bytes):
//   0       : float hdr[3]  { sumsq x[b=0], sumsq x[b=1], sumsq atoms }
//   16      : unsigned candCnt[2]
//   64      : Cand sel[2][KKEEP]                  (16 KB)
//   65536   : unsigned short ab16[1024*2048]      (4 MB, bf16 atoms)
//   4259840 : Cand cand[2][cap]
// ---------------------------------------------------------------------------

__device__ inline unsigned short f2bf(float f) {
    union { float f; unsigned u; } v; v.f = f;
    unsigned r = v.u + 0x7fffu + ((v.u >> 16) & 1u);   // round-to-nearest-even
    return (unsigned short)(r >> 16);
}

__global__ void sums_kernel(const float* __restrict__ x, const float* __restrict__ atoms,
                            float* __restrict__ hdr) {
    const long total = 2L*NS + (long)NA*AL;
    float sx0 = 0.f, sx1 = 0.f, sa = 0.f;
    for (long i = (long)blockIdx.x*blockDim.x + threadIdx.x; i < total;
         i += (long)gridDim.x*blockDim.x) {
        if (i < NS)        { float v = x[i];            sx0 += v*v; }
        else if (i < 2*NS) { float v = x[i];            sx1 += v*v; }
        else               { float v = atoms[i - 2*NS]; sa  += v*v; }
    }
    #pragma unroll
    for (int o = 32; o >= 1; o >>= 1) {
        sx0 += __shfl_down(sx0, o);
        sx1 += __shfl_down(sx1, o);
        sa  += __shfl_down(sa , o);
    }
    if ((threadIdx.x & 63) == 0) {
        if (sx0 != 0.f) atomicAdd(&hdr[0], sx0);
        if (sx1 != 0.f) atomicAdd(&hdr[1], sx1);
        if (sa  != 0.f) atomicAdd(&hdr[2], sa);
    }
}

__global__ void cvt_atoms_kernel(const float* __restrict__ atoms,
                                 unsigned short* __restrict__ ab16) {
    int i = (blockIdx.x * 256 + threadIdx.x) * 4;     // grid covers 2M elems
    float4 f = *(const float4*)(atoms + i);
    ushort4 o;
    o.x = f2bf(f.x); o.y = f2bf(f.y); o.z = f2bf(f.z); o.w = f2bf(f.w);
    *(ushort4*)(ab16 + i) = o;
}

// ---------------------------------------------------------------------------
// MFMA fm kernel.  BM=128 atoms x BN=128 t per block, 4 waves (2m x 2n),
// wave tile 64x64, BK=64 (2 k-steps of 32), mfma_f32_16x16x32_bf16.
//
// B operand (x Toeplitz) read from a REVERSED bf16 x-window in LDS:
// frag elem j = x[t - k] = xr[R + j], R(ni,S) = Rbase - 16*ni + 32*S.
// Rotation identity: R(ni,S+1) = R(ni-2,S)  =>  new frag2 = old frag0,
// new frag3 = old frag1, and frags 0,1 are freshly loaded.  (Round-2 bug:
// rotation was inverted.)
// 8 shifted copies of xr (stride 4368 B == 16 mod 128) give every lane a
// 16B-aligned ds_read_b128.
// A tile staged via global_load_lds(16B) with XOR swizzle applied to the
// per-lane GLOBAL source address (LDS dest linear); reads use
// blk' = blk ^ (row&7)  ->  conflict-free ds_read_b128.
// ---------------------------------------------------------------------------
#define XRW      2175      // reversed-window elements: [t0-2047 .. t0+127]
#define XRSTRIDE 2184      // elems per copy (4368 B: mult of 16, == 16 mod 128)
#define NCPY     8
#define SA_BYTES (128*64*2)

__device__ inline void gload_lds16(const unsigned short* g, unsigned char* lds) {
    __builtin_amdgcn_global_load_lds((const __attribute__((address_space(1))) void*)g,
                                     (__attribute__((address_space(3))) void*)lds,
                                     16, 0, 0);
}

__global__ __launch_bounds__(256, 3)
void fm_kernel(const float* __restrict__ x, const unsigned short* __restrict__ ab16,
               const float* __restrict__ hdr, unsigned* __restrict__ candCnt,
               Cand* __restrict__ cand, unsigned cap)
{
    __shared__ __align__(16) unsigned char  sA[SA_BYTES];
    __shared__ __align__(16) unsigned short sXR[NCPY * XRSTRIDE];

    const int bid = blockIdx.x;
    const int b   = bid >> 11;          // grid = 2 * 8 * 256
    const int rem = bid & 2047;
    const int a0  = (rem >> 8) * 128;
    const int t0  = (rem & 255) * 128;

    const int tid  = threadIdx.x;
    const int lane = tid & 63;
    const int wid  = tid >> 6;
    const int wm   = wid >> 1;          // 0..1 (m 64-block)
    const int wn   = wid & 1;           // 0..1 (n 64-block)
    const int g    = lane >> 4;         // k-group 0..3
    const int ln   = lane & 15;

    const float* __restrict__ xb = x + b * NS;

    // ---- stage reversed x window as bf16, 8 shifted copies ----
    for (int ti = tid; ti < XRW; ti += 256) {
        int t = t0 - 2047 + ti;
        float f = (t >= 0) ? xb[t] : 0.f;
        unsigned short h = f2bf(f);
        int p0 = 2174 - ti;                       // xr[p] = x[t0+127-p]
        #pragma unroll
        for (int m = 0; m < NCPY; ++m) sXR[m * XRSTRIDE + p0 + m] = h;
    }

    f32x4 acc[4][4];
    #pragma unroll
    for (int i = 0; i < 4; ++i)
        #pragma unroll
        for (int j = 0; j < 4; ++j) acc[i][j] = (f32x4)0.0f;

    // lane-constant base: R(ni,S) = Rbase - 16*ni + 32*S
    const int Rbase = 127 - wn * 64 - ln + 8 * g;
    const unsigned char* xrb = (const unsigned char*)sXR;

    __syncthreads();    // xr copies visible to all

    // loadB(R): p = (R+7)&~7 (16B-aligned slot), copy m = p-R
    #define LOADB(Rv) (*(const short8*)(xrb + (unsigned)((((Rv)+7)&~7) - (Rv)) * 4368u \
                                             + (unsigned)(((Rv)+7)&~7) * 2u))

    short8 bA = LOADB(Rbase -  0);     // frag(ni=0, S=0)
    short8 bB = LOADB(Rbase - 16);     // frag(ni=1, S=0)
    short8 bC = LOADB(Rbase - 32);     // frag(ni=2, S=0)
    short8 bD = LOADB(Rbase - 48);     // frag(ni=3, S=0)

    for (int c = 0; c < 32; ++c) {
        const int kc = c * 64;
        __syncthreads();                              // sA reuse guard
        #pragma unroll
        for (int it = 0; it < 4; ++it) {
            int slot = (wid * 4 + it) * 64 + lane;    // 0..1023
            int row  = slot >> 3;                     // 0..127
            int blk  = slot & 7;                      // 16B block in row
            const unsigned short* gsrc =
                ab16 + (size_t)(a0 + row) * AL + kc + ((blk ^ (row & 7)) << 3);
            gload_lds16(gsrc, sA + (size_t)(wid * 4 + it) * 64 * 16);
        }
        __syncthreads();                              // staged data ready

        #pragma unroll
        for (int s = 0; s < 2; ++s) {
            short8 af[4];
            #pragma unroll
            for (int mi = 0; mi < 4; ++mi) {
                int row = wm * 64 + mi * 16 + ln;
                int off = row * 128 + (((s * 4 + g) ^ (row & 7)) << 4);
                af[mi] = *(const short8*)(sA + off);
            }
            #pragma unroll
            for (int mi = 0; mi < 4; ++mi) {
                acc[mi][0] = __builtin_amdgcn_mfma_f32_16x16x32_bf16(af[mi], bA, acc[mi][0], 0, 0, 0);
                acc[mi][1] = __builtin_amdgcn_mfma_f32_16x16x32_bf16(af[mi], bB, acc[mi][1], 0, 0, 0);
                acc[mi][2] = __builtin_amdgcn_mfma_f32_16x16x32_bf16(af[mi], bC, acc[mi][2], 0, 0, 0);
                acc[mi][3] = __builtin_amdgcn_mfma_f32_16x16x32_bf16(af[mi], bD, acc[mi][3], 0, 0, 0);
            }
            // rotate for next k-step: frag(ni,S+1) = frag(ni-2,S)
            // => new frag2/3 = old frag0/1; load new frag0/1.
            int S1 = c * 2 + s + 1;
            if (S1 > 63) S1 = 63;                     // dead prefetch clamp
            short8 nA = LOADB(Rbase      + 32 * S1);  // frag(0,S1)
            short8 nB = LOADB(Rbase - 16 + 32 * S1);  // frag(1,S1)
            bC = bA; bD = bB;
            bA = nA; bB = nB;
        }
    }
    #undef LOADB

    // ---- threshold + candidate append ----
    const float sig = sqrtf((hdr[2] * (1.0f / (float)NA)) * (hdr[b] * (1.0f / (float)NS)));
    const float T0  = 3.0f * sig;

    #pragma unroll
    for (int mi = 0; mi < 4; ++mi) {
        #pragma unroll
        for (int ni = 0; ni < 4; ++ni) {
            #pragma unroll
            for (int r = 0; r < 4; ++r) {
                float v = acc[mi][ni][r];
                if (v > T0) {
                    unsigned a = (unsigned)(a0 + wm * 64 + mi * 16 + g * 4 + r);
                    unsigned t = (unsigned)(t0 + wn * 64 + ni * 16 + ln);
                    unsigned idx = (a << 15) | t;
                    unsigned pos = atomicAdd(&candCnt[b], 1u);
                    if (pos < cap) {
                        Cand cc; cc.v = v; cc.idx = idx;
                        cand[(size_t)b * cap + pos] = cc;
                    }
                }
            }
        }
    }
}

// ---------------------------------------------------------------------------
// Exact fp64 re-evaluation of each candidate (selection authority).
// ---------------------------------------------------------------------------
__global__ void refine_kernel(const float* __restrict__ x, const float* __restrict__ atoms,
                              const unsigned* __restrict__ candCnt, Cand* __restrict__ cand,
                              unsigned cap) {
    const int lane = threadIdx.x & 63;
    const int wid  = (int)((blockIdx.x * blockDim.x + threadIdx.x) >> 6);
    const int nw   = (int)((gridDim.x * blockDim.x) >> 6);
    const int n0 = (int)min(candCnt[0], cap);
    const int n1 = (int)min(candCnt[1], cap);
    const int total = n0 + n1;
    for (int c = wid; c < total; c += nw) {
        const int b = (c < n0) ? 0 : 1;
        const size_t ci = (c < n0) ? (size_t)c : ((size_t)cap + (size_t)(c - n0));
        const unsigned idx = cand[ci].idx;
        const int a = (int)(idx >> 15);
        const int t = (int)(idx & (NS - 1));
        const float* __restrict__ ar = atoms + (size_t)a * AL;
        const float* __restrict__ xr = x + b * NS;
        double s = 0.0;
        for (int k = lane; k < AL; k += 64) {
            int xi = t - k;
            if (xi >= 0) s += (double)ar[k] * (double)xr[xi];
        }
        #pragma unroll
        for (int o = 32; o >= 1; o >>= 1) s += __shfl_down(s, o);
        if (lane == 0) cand[ci].v = (float)s;
    }
}

// ---------------------------------------------------------------------------
// Exact top-KKEEP among candidates (binary search on threshold; ties by
// ascending flat index = jax.lax.top_k semantics). One block per batch.
// ---------------------------------------------------------------------------
__global__ void select_kernel(const unsigned* __restrict__ candCnt,
                              const Cand* __restrict__ cand, Cand* __restrict__ sel,
                              unsigned cap) {
    __shared__ float    s_red[16];
    __shared__ int      s_cnt;
    __shared__ int      s_nA;
    __shared__ int      s_nT;
    __shared__ int      s_exact;
    __shared__ float    s_tau;
    __shared__ Cand     s_A[KKEEP];
    __shared__ unsigned s_T[256];

    const int b = blockIdx.x;
    const Cand* __restrict__ cb = cand + (size_t)b * cap;
    const int n   = (int)min(candCnt[b], cap);
    const int tid = threadIdx.x;

    if (n <= KKEEP) {   // statistically unreachable; safe fallback
        for (int i = tid; i < KKEEP; i += blockDim.x) {
            Cand z; z.v = 0.f; z.idx = 0u;
            sel[b * KKEEP + i] = (i < n) ? cb[i] : z;
        }
        return;
    }

    float m = 0.f;
    for (int i = tid; i < n; i += blockDim.x) m = fmaxf(m, cb[i].v);
    #pragma unroll
    for (int o = 32; o >= 1; o >>= 1) m = fmaxf(m, __shfl_down(m, o));
    if ((tid & 63) == 0) s_red[tid >> 6] = m;
    if (tid == 0) s_exact = 0;
    __syncthreads();
    float hi;
    {
        float mm = 0.f;
        #pragma unroll
        for (int w = 0; w < 16; ++w) mm = fmaxf(mm, s_red[w]);
        hi = mm;
    }
    float lo = 0.f;
    for (int iter = 0; iter < 64; ++iter) {
        float mid = 0.5f * (lo + hi);
        if (!(mid > lo && mid < hi)) break;
        if (tid == 0) s_cnt = 0;
        __syncthreads();
        int c = 0;
        for (int i = tid; i < n; i += blockDim.x) c += (cb[i].v > mid) ? 1 : 0;
        #pragma unroll
        for (int o = 32; o >= 1; o >>= 1) c += __shfl_down(c, o);
        if ((tid & 63) == 0) atomicAdd(&s_cnt, c);
        __syncthreads();
        int cm = s_cnt;
        __syncthreads();
        if (cm == KKEEP) { if (tid == 0) { s_tau = mid; s_exact = 1; } break; }
        if (cm > KKEEP) lo = mid; else hi = mid;
    }
    __syncthreads();

    const int   exact = s_exact;
    const float tau   = exact ? s_tau : hi;

    for (int i = tid; i < KKEEP; i += blockDim.x) { s_A[i].v = 0.f; s_A[i].idx = 0u; }
    if (tid == 0) { s_nA = 0; s_nT = 0; }
    __syncthreads();

    for (int i = tid; i < n; i += blockDim.x) {
        float v = cb[i].v;
        if (v > tau) {
            int p = atomicAdd(&s_nA, 1);
            if (p < KKEEP) s_A[p] = cb[i];
        } else if (!exact && v == tau) {
            int p = atomicAdd(&s_nT, 1);
            if (p < 256) s_T[p] = cb[i].idx;
        }
    }
    __syncthreads();
    if (tid == 0) {
        int nA = s_nA; if (nA > KKEEP) nA = KKEEP;
        int need = KKEEP - nA;
        int nT = s_nT; if (nT > 256) nT = 256;
        for (int r = 0; r < need && r < nT; ++r) {
            unsigned best = 0xffffffffu; int bj = -1;
            for (int j = 0; j < nT; ++j) if (s_T[j] < best) { best = s_T[j]; bj = j; }
            Cand c; c.v = tau; c.idx = best;
            s_A[nA + r] = c;
            if (bj >= 0) s_T[bj] = 0xffffffffu;
        }
    }
    __syncthreads();
    for (int i = tid; i < KKEEP; i += blockDim.x) sel[b * KKEEP + i] = s_A[i];
}

// ---------------------------------------------------------------------------
// recon[b,t] = sum_e val_e * atoms[a_e, t - t0_e]  (gather, deterministic)
// ---------------------------------------------------------------------------
__global__ void recon_kernel(const float* __restrict__ atoms, const Cand* __restrict__ sel,
                             float* __restrict__ out) {
    __shared__ float          s_v[KKEEP];
    __shared__ unsigned short s_a[KKEEP];
    __shared__ unsigned short s_t[KKEEP];
    const int b = blockIdx.x >> 7;
    const int t = ((blockIdx.x & 127) << 8) + threadIdx.x;
    for (int i = threadIdx.x; i < KKEEP; i += blockDim.x) {
        Cand c = sel[b * KKEEP + i];
        s_v[i] = c.v;
        s_a[i] = (unsigned short)(c.idx >> 15);
        s_t[i] = (unsigned short)(c.idx & (NS - 1));
    }
    __syncthreads();
    float acc = 0.f;
    for (int e = 0; e < KKEEP; ++e) {
        int d = t - (int)s_t[e];
        if ((unsigned)d < (unsigned)AL)
            acc += s_v[e] * atoms[(size_t)s_a[e] * AL + d];
    }
    out[b * NS + t] = acc;
}

extern "C" void kernel_launch(void* const* d_in, const int* in_sizes, int n_in,
                              void* d_out, int out_size, void* d_ws, size_t ws_size,
                              hipStream_t stream) {
    const float* x     = (const float*)d_in[0];   // (2,1,32768)
    const float* atoms = (const float*)d_in[1];   // (1,1024,2048)
    float* out = (float*)d_out;                   // (2,1,32768)

    float*          hdr     = (float*)d_ws;
    unsigned*       candCnt = (unsigned*)((char*)d_ws + 16);
    Cand*           sel     = (Cand*)((char*)d_ws + 64);
    unsigned short* ab16    = (unsigned short*)((char*)d_ws + 65536);
    const size_t    candOff = 65536 + (size_t)NA * AL * 2;   // 4,259,840
    Cand*           cand    = (Cand*)((char*)d_ws + candOff);

    unsigned cap = CAPC;
    if (ws_size > candOff + 2 * sizeof(Cand) * 1024) {
        size_t fit = (ws_size - candOff) / (2 * sizeof(Cand));
        if (fit < cap) cap = (unsigned)fit;
    } else {
        cap = 1024;
    }

    hipMemsetAsync(d_ws, 0, 256, stream);  // hdr + counters
    sums_kernel     <<<512, 256, 0, stream>>>(x, atoms, hdr);
    cvt_atoms_kernel<<<(NA * AL) / (256 * 4), 256, 0, stream>>>(atoms, ab16);
    fm_kernel       <<<2 * (NA / 128) * (NS / 128), 256, 0, stream>>>(x, ab16, hdr, candCnt, cand, cap);
    refine_kernel   <<<2048, 256, 0, stream>>>(x, atoms, candCnt, cand, cap);
    select_kernel   <<<2, 1024, 0, stream>>>(candCnt, cand, sel, cap);
    recon_kernel    <<<256, 256, 0, stream>>>(atoms, sel, out);
}

// Round 4
// 603.047 us; speedup vs baseline: 16.1205x; 2.2764x over previous
//
#include <hip/hip_runtime.h>
#include <hip/hip_bf16.h>

#define NS    32768    // samples
#define NA    1024     // atoms
#define AL    2048     // atom length
#define KKEEP 1024     // top-k
#define CAPC  (512*1024)

struct Cand { float v; unsigned idx; };

typedef short  short8 __attribute__((ext_vector_type(8)));
typedef float  f32x4  __attribute__((ext_vector_type(4)));

// ---------------------------------------------------------------------------
// ws layout (bytes):
//   0       : float hdr[3]  { sumsq x[b=0], sumsq x[b=1], sumsq atoms }
//   16      : unsigned candCnt[2]
//   64      : Cand sel[2][KKEEP]                  (16 KB)
//   65536   : unsigned short ab16[1024*2048]      (4 MB, bf16 atoms)
//   4259840 : Cand cand[2][cap]
// ---------------------------------------------------------------------------

__device__ inline unsigned short f2bf(float f) {
    union { float f; unsigned u; } v; v.f = f;
    unsigned r = v.u + 0x7fffu + ((v.u >> 16) & 1u);   // round-to-nearest-even
    return (unsigned short)(r >> 16);
}

__global__ void sums_kernel(const float* __restrict__ x, const float* __restrict__ atoms,
                            float* __restrict__ hdr) {
    const long total = 2L*NS + (long)NA*AL;
    float sx0 = 0.f, sx1 = 0.f, sa = 0.f;
    for (long i = (long)blockIdx.x*blockDim.x + threadIdx.x; i < total;
         i += (long)gridDim.x*blockDim.x) {
        if (i < NS)        { float v = x[i];            sx0 += v*v; }
        else if (i < 2*NS) { float v = x[i];            sx1 += v*v; }
        else               { float v = atoms[i - 2*NS]; sa  += v*v; }
    }
    #pragma unroll
    for (int o = 32; o >= 1; o >>= 1) {
        sx0 += __shfl_down(sx0, o);
        sx1 += __shfl_down(sx1, o);
        sa  += __shfl_down(sa , o);
    }
    if ((threadIdx.x & 63) == 0) {
        if (sx0 != 0.f) atomicAdd(&hdr[0], sx0);
        if (sx1 != 0.f) atomicAdd(&hdr[1], sx1);
        if (sa  != 0.f) atomicAdd(&hdr[2], sa);
    }
}

__global__ void cvt_atoms_kernel(const float* __restrict__ atoms,
                                 unsigned short* __restrict__ ab16) {
    int i = (blockIdx.x * 256 + threadIdx.x) * 4;     // grid covers 2M elems
    float4 f = *(const float4*)(atoms + i);
    ushort4 o;
    o.x = f2bf(f.x); o.y = f2bf(f.y); o.z = f2bf(f.z); o.w = f2bf(f.w);
    *(ushort4*)(ab16 + i) = o;
}

// ---------------------------------------------------------------------------
// MFMA fm kernel, 2-phase pipelined (T3 minimum form):
//   prologue: STAGE(buf0, first chunk); barrier;
//   loop:     STAGE(buf^1, next chunk); compute(buf); barrier; buf^=1;
// One vmcnt(0)+barrier per K-chunk (compiler emits it before s_barrier), so
// the load drain is overlapped by a full compute phase.  K-chunk order is
// rotated per block ((c+rot)&31) to de-convoy L2 (accumulation is order-
// independent; B-frag rolling handles the wrap with a full reload).
//
// B operand (x Toeplitz) read from a REVERSED bf16 x-window in LDS:
// frag elem j = x[t-k] = xr[R+j], R(ni,S) = Rbase - 16*ni + 32*S.
// Rolling identity: frag(ni,S+1) = frag(ni-2,S).
// 8 shifted copies of xr (stride 4368 B == 16 mod 128): every lane gets an
// aligned ds_read_b128.  A tile staged via global_load_lds(16B), XOR swizzle
// folded into the per-lane GLOBAL source address (LDS dest linear).
// ---------------------------------------------------------------------------
#define XRW      2175      // reversed-window elements: [t0-2047 .. t0+127]
#define XRSTRIDE 2184      // elems per copy (4368 B: mult of 16, == 16 mod 128)
#define NCPY     8
#define SA_BUF   16384     // bytes per A buffer (128 rows x 8 blk x 16B)

__device__ inline void gload_lds16(const unsigned short* g, unsigned char* lds) {
    __builtin_amdgcn_global_load_lds((const __attribute__((address_space(1))) void*)g,
                                     (__attribute__((address_space(3))) void*)lds,
                                     16, 0, 0);
}

__global__ __launch_bounds__(256, 2)
void fm_kernel(const float* __restrict__ x, const unsigned short* __restrict__ ab16,
               const float* __restrict__ hdr, unsigned* __restrict__ candCnt,
               Cand* __restrict__ cand, unsigned cap)
{
    __shared__ __align__(16) unsigned char  sA[2 * SA_BUF];
    __shared__ __align__(16) unsigned short sXR[NCPY * XRSTRIDE];

    const int bid = blockIdx.x;
    const int b   = bid >> 11;          // grid = 2 * 8 * 256
    const int rem = bid & 2047;
    const int a0  = (rem >> 8) * 128;
    const int t0  = (rem & 255) * 128;

    const int tid  = threadIdx.x;
    const int lane = tid & 63;
    const int wid  = tid >> 6;
    const int wm   = wid >> 1;          // 0..1 (m 64-block)
    const int wn   = wid & 1;           // 0..1 (n 64-block)
    const int g    = lane >> 4;         // k-group 0..3
    const int ln   = lane & 15;

    const int rot = (bid * 5) & 31;     // per-block K-chunk rotation

    const float* __restrict__ xb = x + b * NS;

    // ---- stage reversed x window as bf16, 8 shifted copies ----
    for (int ti = tid; ti < XRW; ti += 256) {
        int t = t0 - 2047 + ti;
        float f = (t >= 0) ? xb[t] : 0.f;
        unsigned short h = f2bf(f);
        int p0 = 2174 - ti;                       // xr[p] = x[t0+127-p]
        #pragma unroll
        for (int m = 0; m < NCPY; ++m) sXR[m * XRSTRIDE + p0 + m] = h;
    }

    // stage A chunk `ck` (64 k-elems) into buffer `bf`
    #define STAGE(bf, ck) do {                                                   \
        int kcs = (ck) * 64;                                                     \
        _Pragma("unroll")                                                        \
        for (int it = 0; it < 4; ++it) {                                         \
            int slot = (wid * 4 + it) * 64 + lane;                               \
            int row  = slot >> 3;                                                \
            int blk  = slot & 7;                                                 \
            const unsigned short* gsrc =                                         \
                ab16 + (size_t)(a0 + row) * AL + kcs + ((blk ^ (row & 7)) << 3); \
            gload_lds16(gsrc, sA + (bf) * SA_BUF + (size_t)(wid * 4 + it) * 1024); \
        }                                                                        \
    } while (0)

    f32x4 acc[4][4];
    #pragma unroll
    for (int i = 0; i < 4; ++i)
        #pragma unroll
        for (int j = 0; j < 4; ++j) acc[i][j] = (f32x4)0.0f;

    // lane-constant base: R(ni,S) = Rbase - 16*ni + 32*S
    const int Rbase = 127 - wn * 64 - ln + 8 * g;
    const unsigned char* xrb = (const unsigned char*)sXR;

    // loadB(R): p = (R+7)&~7 (16B-aligned slot), copy m = p-R
    #define LOADB(Rv) (*(const short8*)(xrb + (unsigned)((((Rv)+7)&~7) - (Rv)) * 4368u \
                                             + (unsigned)(((Rv)+7)&~7) * 2u))

    STAGE(0, rot);            // prologue stage
    __syncthreads();          // xr copies + first A chunk visible

    const int S0 = rot * 2;
    short8 bA = LOADB(Rbase      + 32 * S0);   // frag(0,S0)
    short8 bB = LOADB(Rbase - 16 + 32 * S0);   // frag(1,S0)
    short8 bC = LOADB(Rbase - 32 + 32 * S0);   // frag(2,S0)
    short8 bD = LOADB(Rbase - 48 + 32 * S0);   // frag(3,S0)

    int cur = 0;
    for (int c = 0; c < 32; ++c) {
        const int chunk  = (c + rot) & 31;
        const int nchunk = (c + 1 + rot) & 31;
        if (c + 1 < 32) STAGE(cur ^ 1, nchunk);     // prefetch next chunk

        #pragma unroll
        for (int s = 0; s < 2; ++s) {
            short8 af[4];
            #pragma unroll
            for (int mi = 0; mi < 4; ++mi) {
                int row = wm * 64 + mi * 16 + ln;
                int off = cur * SA_BUF + row * 128 + (((s * 4 + g) ^ (row & 7)) << 4);
                af[mi] = *(const short8*)(sA + off);
            }
            #pragma unroll
            for (int mi = 0; mi < 4; ++mi) {
                acc[mi][0] = __builtin_amdgcn_mfma_f32_16x16x32_bf16(af[mi], bA, acc[mi][0], 0, 0, 0);
                acc[mi][1] = __builtin_amdgcn_mfma_f32_16x16x32_bf16(af[mi], bB, acc[mi][1], 0, 0, 0);
                acc[mi][2] = __builtin_amdgcn_mfma_f32_16x16x32_bf16(af[mi], bC, acc[mi][2], 0, 0, 0);
                acc[mi][3] = __builtin_amdgcn_mfma_f32_16x16x32_bf16(af[mi], bD, acc[mi][3], 0, 0, 0);
            }
            // B-frag update for next k-step
            if (s == 0) {
                // next S = chunk*2+1 (always consecutive): frag(ni,S+1)=frag(ni-2,S)
                int Sn = chunk * 2 + 1;
                short8 nA = LOADB(Rbase      + 32 * Sn);
                short8 nB = LOADB(Rbase - 16 + 32 * Sn);
                bC = bA; bD = bB;
                bA = nA; bB = nB;
            } else {
                int Sn = nchunk * 2;                  // next c's first k-step
                if (nchunk == 0) {                    // wrap (or dead tail): full reload
                    bA = LOADB(Rbase      + 32 * Sn);
                    bB = LOADB(Rbase - 16 + 32 * Sn);
                    bC = LOADB(Rbase - 32 + 32 * Sn);
                    bD = LOADB(Rbase - 48 + 32 * Sn);
                } else {                              // consecutive: roll
                    short8 nA = LOADB(Rbase      + 32 * Sn);
                    short8 nB = LOADB(Rbase - 16 + 32 * Sn);
                    bC = bA; bD = bB;
                    bA = nA; bB = nB;
                }
            }
        }
        __syncthreads();      // drains my gloads (vmcnt0) + everyone's ds reads
        cur ^= 1;
    }
    #undef LOADB
    #undef STAGE

    // ---- threshold + candidate append ----
    const float sig = sqrtf((hdr[2] * (1.0f / (float)NA)) * (hdr[b] * (1.0f / (float)NS)));
    const float T0  = 3.35f * sig;   // cutoff ~4sigma; bf16 noise ~0.006sigma

    #pragma unroll
    for (int mi = 0; mi < 4; ++mi) {
        #pragma unroll
        for (int ni = 0; ni < 4; ++ni) {
            #pragma unroll
            for (int r = 0; r < 4; ++r) {
                float v = acc[mi][ni][r];
                if (v > T0) {
                    unsigned a = (unsigned)(a0 + wm * 64 + mi * 16 + g * 4 + r);
                    unsigned t = (unsigned)(t0 + wn * 64 + ni * 16 + ln);
                    unsigned idx = (a << 15) | t;
                    unsigned pos = atomicAdd(&candCnt[b], 1u);
                    if (pos < cap) {
                        Cand cc; cc.v = v; cc.idx = idx;
                        cand[(size_t)b * cap + pos] = cc;
                    }
                }
            }
        }
    }
}

// ---------------------------------------------------------------------------
// Exact fp64 re-evaluation of each candidate (selection authority).
// ---------------------------------------------------------------------------
__global__ void refine_kernel(const float* __restrict__ x, const float* __restrict__ atoms,
                              const unsigned* __restrict__ candCnt, Cand* __restrict__ cand,
                              unsigned cap) {
    const int lane = threadIdx.x & 63;
    const int wid  = (int)((blockIdx.x * blockDim.x + threadIdx.x) >> 6);
    const int nw   = (int)((gridDim.x * blockDim.x) >> 6);
    const int n0 = (int)min(candCnt[0], cap);
    const int n1 = (int)min(candCnt[1], cap);
    const int total = n0 + n1;
    for (int c = wid; c < total; c += nw) {
        const int b = (c < n0) ? 0 : 1;
        const size_t ci = (c < n0) ? (size_t)c : ((size_t)cap + (size_t)(c - n0));
        const unsigned idx = cand[ci].idx;
        const int a = (int)(idx >> 15);
        const int t = (int)(idx & (NS - 1));
        const float* __restrict__ ar = atoms + (size_t)a * AL;
        const float* __restrict__ xr = x + b * NS;
        double s = 0.0;
        for (int k = lane; k < AL; k += 64) {
            int xi = t - k;
            if (xi >= 0) s += (double)ar[k] * (double)xr[xi];
        }
        #pragma unroll
        for (int o = 32; o >= 1; o >>= 1) s += __shfl_down(s, o);
        if (lane == 0) cand[ci].v = (float)s;
    }
}

// ---------------------------------------------------------------------------
// Exact top-KKEEP among candidates (binary search on threshold; ties by
// ascending flat index = jax.lax.top_k semantics). One block per batch.
// ---------------------------------------------------------------------------
__global__ void select_kernel(const unsigned* __restrict__ candCnt,
                              const Cand* __restrict__ cand, Cand* __restrict__ sel,
                              unsigned cap) {
    __shared__ float    s_red[16];
    __shared__ int      s_cnt;
    __shared__ int      s_nA;
    __shared__ int      s_nT;
    __shared__ int      s_exact;
    __shared__ float    s_tau;
    __shared__ Cand     s_A[KKEEP];
    __shared__ unsigned s_T[256];

    const int b = blockIdx.x;
    const Cand* __restrict__ cb = cand + (size_t)b * cap;
    const int n   = (int)min(candCnt[b], cap);
    const int tid = threadIdx.x;

    if (n <= KKEEP) {   // statistically unreachable; safe fallback
        for (int i = tid; i < KKEEP; i += blockDim.x) {
            Cand z; z.v = 0.f; z.idx = 0u;
            sel[b * KKEEP + i] = (i < n) ? cb[i] : z;
        }
        return;
    }

    float m = 0.f;
    for (int i = tid; i < n; i += blockDim.x) m = fmaxf(m, cb[i].v);
    #pragma unroll
    for (int o = 32; o >= 1; o >>= 1) m = fmaxf(m, __shfl_down(m, o));
    if ((tid & 63) == 0) s_red[tid >> 6] = m;
    if (tid == 0) s_exact = 0;
    __syncthreads();
    float hi;
    {
        float mm = 0.f;
        #pragma unroll
        for (int w = 0; w < 16; ++w) mm = fmaxf(mm, s_red[w]);
        hi = mm;
    }
    float lo = 0.f;
    for (int iter = 0; iter < 64; ++iter) {
        float mid = 0.5f * (lo + hi);
        if (!(mid > lo && mid < hi)) break;
        if (tid == 0) s_cnt = 0;
        __syncthreads();
        int c = 0;
        for (int i = tid; i < n; i += blockDim.x) c += (cb[i].v > mid) ? 1 : 0;
        #pragma unroll
        for (int o = 32; o >= 1; o >>= 1) c += __shfl_down(c, o);
        if ((tid & 63) == 0) atomicAdd(&s_cnt, c);
        __syncthreads();
        int cm = s_cnt;
        __syncthreads();
        if (cm == KKEEP) { if (tid == 0) { s_tau = mid; s_exact = 1; } break; }
        if (cm > KKEEP) lo = mid; else hi = mid;
    }
    __syncthreads();

    const int   exact = s_exact;
    const float tau   = exact ? s_tau : hi;

    for (int i = tid; i < KKEEP; i += blockDim.x) { s_A[i].v = 0.f; s_A[i].idx = 0u; }
    if (tid == 0) { s_nA = 0; s_nT = 0; }
    __syncthreads();

    for (int i = tid; i < n; i += blockDim.x) {
        float v = cb[i].v;
        if (v > tau) {
            int p = atomicAdd(&s_nA, 1);
            if (p < KKEEP) s_A[p] = cb[i];
        } else if (!exact && v == tau) {
            int p = atomicAdd(&s_nT, 1);
            if (p < 256) s_T[p] = cb[i].idx;
        }
    }
    __syncthreads();
    if (tid == 0) {
        int nA = s_nA; if (nA > KKEEP) nA = KKEEP;
        int need = KKEEP - nA;
        int nT = s_nT; if (nT > 256) nT = 256;
        for (int r = 0; r < need && r < nT; ++r) {
            unsigned best = 0xffffffffu; int bj = -1;
            for (int j = 0; j < nT; ++j) if (s_T[j] < best) { best = s_T[j]; bj = j; }
            Cand c; c.v = tau; c.idx = best;
            s_A[nA + r] = c;
            if (bj >= 0) s_T[bj] = 0xffffffffu;
        }
    }
    __syncthreads();
    for (int i = tid; i < KKEEP; i += blockDim.x) sel[b * KKEEP + i] = s_A[i];
}

// ---------------------------------------------------------------------------
// recon[b,t] = sum_e val_e * atoms[a_e, t - t0_e]  (gather, deterministic)
// ---------------------------------------------------------------------------
__global__ void recon_kernel(const float* __restrict__ atoms, const Cand* __restrict__ sel,
                             float* __restrict__ out) {
    __shared__ float          s_v[KKEEP];
    __shared__ unsigned short s_a[KKEEP];
    __shared__ unsigned short s_t[KKEEP];
    const int b = blockIdx.x >> 7;
    const int t = ((blockIdx.x & 127) << 8) + threadIdx.x;
    for (int i = threadIdx.x; i < KKEEP; i += blockDim.x) {
        Cand c = sel[b * KKEEP + i];
        s_v[i] = c.v;
        s_a[i] = (unsigned short)(c.idx >> 15);
        s_t[i] = (unsigned short)(c.idx & (NS - 1));
    }
    __syncthreads();
    float acc = 0.f;
    for (int e = 0; e < KKEEP; ++e) {
        int d = t - (int)s_t[e];
        if ((unsigned)d < (unsigned)AL)
            acc += s_v[e] * atoms[(size_t)s_a[e] * AL + d];
    }
    out[b * NS + t] = acc;
}

extern "C" void kernel_launch(void* const* d_in, const int* in_sizes, int n_in,
                              void* d_out, int out_size, void* d_ws, size_t ws_size,
                              hipStream_t stream) {
    const float* x     = (const float*)d_in[0];   // (2,1,32768)
    const float* atoms = (const float*)d_in[1];   // (1,1024,2048)
    float* out = (float*)d_out;                   // (2,1,32768)

    float*          hdr     = (float*)d_ws;
    unsigned*       candCnt = (unsigned*)((char*)d_ws + 16);
    Cand*           sel     = (Cand*)((char*)d_ws + 64);
    unsigned short* ab16    = (unsigned short*)((char*)d_ws + 65536);
    const size_t    candOff = 65536 + (size_t)NA * AL * 2;   // 4,259,840
    Cand*           cand    = (Cand*)((char*)d_ws + candOff);

    unsigned cap = CAPC;
    if (ws_size > candOff + 2 * sizeof(Cand) * 1024) {
        size_t fit = (ws_size - candOff) / (2 * sizeof(Cand));
        if (fit < cap) cap = (unsigned)fit;
    } else {
        cap = 1024;
    }

    hipMemsetAsync(d_ws, 0, 256, stream);  // hdr + counters
    sums_kernel     <<<512, 256, 0, stream>>>(x, atoms, hdr);
    cvt_atoms_kernel<<<(NA * AL) / (256 * 4), 256, 0, stream>>>(atoms, ab16);
    fm_kernel       <<<2 * (NA / 128) * (NS / 128), 256, 0, stream>>>(x, ab16, hdr, candCnt, cand, cap);
    refine_kernel   <<<2048, 256, 0, stream>>>(x, atoms, candCnt, cand, cap);
    select_kernel   <<<2, 1024, 0, stream>>>(candCnt, cand, sel, cap);
    recon_kernel    <<<256, 256, 0, stream>>>(atoms, sel, out);
}

// Round 5
// 577.966 us; speedup vs baseline: 16.8201x; 1.0434x over previous
//
#include <hip/hip_runtime.h>
#include <hip/hip_bf16.h>

#define NS    32768    // samples
#define NA    1024     // atoms
#define AL    2048     // atom length
#define KKEEP 1024     // top-k
#define CAPC  (512*1024)

struct Cand { float v; unsigned idx; };

typedef short  short8 __attribute__((ext_vector_type(8)));
typedef float  f32x4  __attribute__((ext_vector_type(4)));

// ---------------------------------------------------------------------------
// ws layout (bytes):
//   0       : float hdr[3]  { sumsq x[b=0], sumsq x[b=1], sumsq atoms }
//   16      : unsigned candCnt[2]
//   64      : Cand sel[2][KKEEP]                  (16 KB)
//   65536   : unsigned short ab16[1024*2048]      (4 MB, bf16 atoms)
//   4259840 : Cand cand[2][cap]
// ---------------------------------------------------------------------------

__device__ inline unsigned short f2bf(float f) {
    union { float f; unsigned u; } v; v.f = f;
    unsigned r = v.u + 0x7fffu + ((v.u >> 16) & 1u);   // round-to-nearest-even
    return (unsigned short)(r >> 16);
}

__global__ void sums_kernel(const float* __restrict__ x, const float* __restrict__ atoms,
                            float* __restrict__ hdr) {
    const long total = 2L*NS + (long)NA*AL;
    float sx0 = 0.f, sx1 = 0.f, sa = 0.f;
    for (long i = (long)blockIdx.x*blockDim.x + threadIdx.x; i < total;
         i += (long)gridDim.x*blockDim.x) {
        if (i < NS)        { float v = x[i];            sx0 += v*v; }
        else if (i < 2*NS) { float v = x[i];            sx1 += v*v; }
        else               { float v = atoms[i - 2*NS]; sa  += v*v; }
    }
    #pragma unroll
    for (int o = 32; o >= 1; o >>= 1) {
        sx0 += __shfl_down(sx0, o);
        sx1 += __shfl_down(sx1, o);
        sa  += __shfl_down(sa , o);
    }
    if ((threadIdx.x & 63) == 0) {
        if (sx0 != 0.f) atomicAdd(&hdr[0], sx0);
        if (sx1 != 0.f) atomicAdd(&hdr[1], sx1);
        if (sa  != 0.f) atomicAdd(&hdr[2], sa);
    }
}

__global__ void cvt_atoms_kernel(const float* __restrict__ atoms,
                                 unsigned short* __restrict__ ab16) {
    int i = (blockIdx.x * 256 + threadIdx.x) * 4;     // grid covers 2M elems
    float4 f = *(const float4*)(atoms + i);
    ushort4 o;
    o.x = f2bf(f.x); o.y = f2bf(f.y); o.z = f2bf(f.z); o.w = f2bf(f.w);
    *(ushort4*)(ab16 + i) = o;
}

// ---------------------------------------------------------------------------
// MFMA fm kernel, 2-phase pipelined, block tile 128 atoms x 256 t,
// 4 waves (2m x 2n), wave tile 64x128: acc[4][8], 32 MFMA per k-step vs
// 6 ds_read_b128 (4 A + 2 rolled B)  -> 2x arithmetic intensity per LDS byte
// vs round 4 (which was LDS-throughput-bound at MfmaUtil 30%).
//
// B operand (x Toeplitz) from REVERSED bf16 x-window in LDS:
// frag elem j = xr[R+j], R(ni,S) = Rbase - 16*ni + 32*S,
// Rbase = 255 - wn*128 - ln + 8*g, xr[p] = x[t0+255-p].
// Rolling identity: frag(ni,S+1) = frag(ni-2,S) -> only ni=0,1 fresh/k-step.
// 8 shifted copies (stride 4624 B == 16 mod 128) -> aligned ds_read_b128.
// A tile staged via global_load_lds(16B), XOR swizzle folded into the
// per-lane GLOBAL source address (LDS dest linear).  K-chunk order rotated
// per block ((c+rot)&31) to de-convoy L2.
// ---------------------------------------------------------------------------
#define XRW      2303      // reversed-window elements: [t0-2047 .. t0+255]
#define XRSTRIDE 2312      // elems per copy (4624 B: mult of 16, == 16 mod 128)
#define XRB      4624
#define NCPY     8
#define SA_BUF   16384     // bytes per A buffer (128 rows x 8 blk x 16B)

__device__ inline void gload_lds16(const unsigned short* g, unsigned char* lds) {
    __builtin_amdgcn_global_load_lds((const __attribute__((address_space(1))) void*)g,
                                     (__attribute__((address_space(3))) void*)lds,
                                     16, 0, 0);
}

__global__ __launch_bounds__(256, 2)
void fm_kernel(const float* __restrict__ x, const unsigned short* __restrict__ ab16,
               const float* __restrict__ hdr, unsigned* __restrict__ candCnt,
               Cand* __restrict__ cand, unsigned cap)
{
    __shared__ __align__(16) unsigned char  sA[2 * SA_BUF];
    __shared__ __align__(16) unsigned short sXR[NCPY * XRSTRIDE];

    const int bid = blockIdx.x;
    const int b   = bid >> 10;          // grid = 2 * 8 * 128
    const int rem = bid & 1023;
    const int a0  = (rem >> 7) * 128;
    const int t0  = (rem & 127) * 256;

    const int tid  = threadIdx.x;
    const int lane = tid & 63;
    const int wid  = tid >> 6;
    const int wm   = wid >> 1;          // 0..1 (m 64-block)
    const int wn   = wid & 1;           // 0..1 (n 128-block)
    const int g    = lane >> 4;         // k-group 0..3
    const int ln   = lane & 15;

    const int rot = (bid * 5) & 31;     // per-block K-chunk rotation

    const float* __restrict__ xb = x + b * NS;

    // ---- stage reversed x window as bf16, 8 shifted copies ----
    for (int ti = tid; ti < XRW; ti += 256) {
        int t = t0 - 2047 + ti;
        float f = (t >= 0 && t < NS) ? xb[t] : 0.f;
        unsigned short h = f2bf(f);
        int p0 = 2302 - ti;                       // xr[p] = x[t0+255-p]
        #pragma unroll
        for (int m = 0; m < NCPY; ++m) sXR[m * XRSTRIDE + p0 + m] = h;
    }

    // stage A chunk `ck` (64 k-elems) into buffer `bf`
    #define STAGE(bf, ck) do {                                                   \
        int kcs = (ck) * 64;                                                     \
        _Pragma("unroll")                                                        \
        for (int it = 0; it < 4; ++it) {                                         \
            int slot = (wid * 4 + it) * 64 + lane;                               \
            int row  = slot >> 3;                                                \
            int blk  = slot & 7;                                                 \
            const unsigned short* gsrc =                                         \
                ab16 + (size_t)(a0 + row) * AL + kcs + ((blk ^ (row & 7)) << 3); \
            gload_lds16(gsrc, sA + (bf) * SA_BUF + (size_t)(wid * 4 + it) * 1024); \
        }                                                                        \
    } while (0)

    f32x4 acc[4][8];
    #pragma unroll
    for (int i = 0; i < 4; ++i)
        #pragma unroll
        for (int j = 0; j < 8; ++j) acc[i][j] = (f32x4)0.0f;

    // lane-constant base: R(ni,S) = Rbase - 16*ni + 32*S
    const int Rbase = 255 - wn * 128 - ln + 8 * g;
    const unsigned char* xrb = (const unsigned char*)sXR;

    // loadB(R): p = (R+7)&~7 (16B-aligned slot), copy m = p-R
    #define LOADB(Rv) (*(const short8*)(xrb + (unsigned)((((Rv)+7)&~7) - (Rv)) * XRB \
                                             + (unsigned)(((Rv)+7)&~7) * 2u))

    short8 b0, b1, b2, b3, b4, b5, b6, b7;

    #define LOADB8(Sv) do {                       \
        b0 = LOADB(Rbase       + 32 * (Sv));      \
        b1 = LOADB(Rbase - 16  + 32 * (Sv));      \
        b2 = LOADB(Rbase - 32  + 32 * (Sv));      \
        b3 = LOADB(Rbase - 48  + 32 * (Sv));      \
        b4 = LOADB(Rbase - 64  + 32 * (Sv));      \
        b5 = LOADB(Rbase - 80  + 32 * (Sv));      \
        b6 = LOADB(Rbase - 96  + 32 * (Sv));      \
        b7 = LOADB(Rbase - 112 + 32 * (Sv));      \
    } while (0)

    // frag(ni,S+1) = frag(ni-2,S): shift chain + 2 fresh
    #define ROLLB(Sv) do {                        \
        b7 = b5; b6 = b4; b5 = b3; b4 = b2;       \
        b3 = b1; b2 = b0;                         \
        b0 = LOADB(Rbase      + 32 * (Sv));       \
        b1 = LOADB(Rbase - 16 + 32 * (Sv));       \
    } while (0)

    #define MFMAS(mi) do {                                                                  \
        acc[mi][0] = __builtin_amdgcn_mfma_f32_16x16x32_bf16(af[mi], b0, acc[mi][0],0,0,0); \
        acc[mi][1] = __builtin_amdgcn_mfma_f32_16x16x32_bf16(af[mi], b1, acc[mi][1],0,0,0); \
        acc[mi][2] = __builtin_amdgcn_mfma_f32_16x16x32_bf16(af[mi], b2, acc[mi][2],0,0,0); \
        acc[mi][3] = __builtin_amdgcn_mfma_f32_16x16x32_bf16(af[mi], b3, acc[mi][3],0,0,0); \
        acc[mi][4] = __builtin_amdgcn_mfma_f32_16x16x32_bf16(af[mi], b4, acc[mi][4],0,0,0); \
        acc[mi][5] = __builtin_amdgcn_mfma_f32_16x16x32_bf16(af[mi], b5, acc[mi][5],0,0,0); \
        acc[mi][6] = __builtin_amdgcn_mfma_f32_16x16x32_bf16(af[mi], b6, acc[mi][6],0,0,0); \
        acc[mi][7] = __builtin_amdgcn_mfma_f32_16x16x32_bf16(af[mi], b7, acc[mi][7],0,0,0); \
    } while (0)

    STAGE(0, rot);            // prologue stage
    __syncthreads();          // xr copies + first A chunk visible

    LOADB8(rot * 2);

    int cur = 0;
    for (int c = 0; c < 32; ++c) {
        const int chunk  = (c + rot) & 31;
        const int nchunk = (c + 1 + rot) & 31;
        if (c + 1 < 32) STAGE(cur ^ 1, nchunk);     // prefetch next chunk

        #pragma unroll
        for (int s = 0; s < 2; ++s) {
            short8 af[4];
            #pragma unroll
            for (int mi = 0; mi < 4; ++mi) {
                int row = wm * 64 + mi * 16 + ln;
                int off = cur * SA_BUF + row * 128 + (((s * 4 + g) ^ (row & 7)) << 4);
                af[mi] = *(const short8*)(sA + off);
            }
            MFMAS(0); MFMAS(1); MFMAS(2); MFMAS(3);

            if (s == 0) {
                ROLLB(chunk * 2 + 1);
            } else {
                if (nchunk == 0) { LOADB8(0); }     // wrap (or dead tail)
                else             { ROLLB(nchunk * 2); }
            }
        }
        __syncthreads();      // drains my gloads (vmcnt0) + everyone's ds reads
        cur ^= 1;
    }
    #undef LOADB
    #undef LOADB8
    #undef ROLLB
    #undef MFMAS
    #undef STAGE

    // ---- threshold + candidate append ----
    const float sig = sqrtf((hdr[2] * (1.0f / (float)NA)) * (hdr[b] * (1.0f / (float)NS)));
    const float T0  = 3.35f * sig;   // cutoff ~4sigma; bf16 noise ~0.006sigma

    #pragma unroll
    for (int mi = 0; mi < 4; ++mi) {
        #pragma unroll
        for (int ni = 0; ni < 8; ++ni) {
            #pragma unroll
            for (int r = 0; r < 4; ++r) {
                float v = acc[mi][ni][r];
                if (v > T0) {
                    unsigned a = (unsigned)(a0 + wm * 64 + mi * 16 + g * 4 + r);
                    unsigned t = (unsigned)(t0 + wn * 128 + ni * 16 + ln);
                    unsigned idx = (a << 15) | t;
                    unsigned pos = atomicAdd(&candCnt[b], 1u);
                    if (pos < cap) {
                        Cand cc; cc.v = v; cc.idx = idx;
                        cand[(size_t)b * cap + pos] = cc;
                    }
                }
            }
        }
    }
}

// ---------------------------------------------------------------------------
// Exact fp64 re-evaluation of each candidate (selection authority).
// ---------------------------------------------------------------------------
__global__ void refine_kernel(const float* __restrict__ x, const float* __restrict__ atoms,
                              const unsigned* __restrict__ candCnt, Cand* __restrict__ cand,
                              unsigned cap) {
    const int lane = threadIdx.x & 63;
    const int wid  = (int)((blockIdx.x * blockDim.x + threadIdx.x) >> 6);
    const int nw   = (int)((gridDim.x * blockDim.x) >> 6);
    const int n0 = (int)min(candCnt[0], cap);
    const int n1 = (int)min(candCnt[1], cap);
    const int total = n0 + n1;
    for (int c = wid; c < total; c += nw) {
        const int b = (c < n0) ? 0 : 1;
        const size_t ci = (c < n0) ? (size_t)c : ((size_t)cap + (size_t)(c - n0));
        const unsigned idx = cand[ci].idx;
        const int a = (int)(idx >> 15);
        const int t = (int)(idx & (NS - 1));
        const float* __restrict__ ar = atoms + (size_t)a * AL;
        const float* __restrict__ xr = x + b * NS;
        double s = 0.0;
        for (int k = lane; k < AL; k += 64) {
            int xi = t - k;
            if (xi >= 0) s += (double)ar[k] * (double)xr[xi];
        }
        #pragma unroll
        for (int o = 32; o >= 1; o >>= 1) s += __shfl_down(s, o);
        if (lane == 0) cand[ci].v = (float)s;
    }
}

// ---------------------------------------------------------------------------
// Exact top-KKEEP among candidates (binary search on threshold; ties by
// ascending flat index = jax.lax.top_k semantics). One block per batch.
// Candidate values cached in LDS for the search sweeps.
// ---------------------------------------------------------------------------
#define SELCAP 16384

__global__ void select_kernel(const unsigned* __restrict__ candCnt,
                              const Cand* __restrict__ cand, Cand* __restrict__ sel,
                              unsigned cap) {
    __shared__ float    s_vals[SELCAP];
    __shared__ float    s_red[16];
    __shared__ int      s_cnt;
    __shared__ int      s_nA;
    __shared__ int      s_nT;
    __shared__ int      s_exact;
    __shared__ float    s_tau;
    __shared__ Cand     s_A[KKEEP];
    __shared__ unsigned s_T[256];

    const int b = blockIdx.x;
    const Cand* __restrict__ cb = cand + (size_t)b * cap;
    const int n   = (int)min(candCnt[b], cap);
    const int tid = threadIdx.x;

    if (n <= KKEEP) {   // statistically unreachable; safe fallback
        for (int i = tid; i < KKEEP; i += blockDim.x) {
            Cand z; z.v = 0.f; z.idx = 0u;
            sel[b * KKEEP + i] = (i < n) ? cb[i] : z;
        }
        return;
    }

    const bool useLds = (n <= SELCAP);
    if (useLds)
        for (int i = tid; i < n; i += blockDim.x) s_vals[i] = cb[i].v;

    float m = 0.f;
    if (useLds) { __syncthreads();
        for (int i = tid; i < n; i += blockDim.x) m = fmaxf(m, s_vals[i]);
    } else {
        for (int i = tid; i < n; i += blockDim.x) m = fmaxf(m, cb[i].v);
    }
    #pragma unroll
    for (int o = 32; o >= 1; o >>= 1) m = fmaxf(m, __shfl_down(m, o));
    if ((tid & 63) == 0) s_red[tid >> 6] = m;
    if (tid == 0) s_exact = 0;
    __syncthreads();
    float hi;
    {
        float mm = 0.f;
        #pragma unroll
        for (int w = 0; w < 16; ++w) mm = fmaxf(mm, s_red[w]);
        hi = mm;
    }
    float lo = 0.f;
    for (int iter = 0; iter < 64; ++iter) {
        float mid = 0.5f * (lo + hi);
        if (!(mid > lo && mid < hi)) break;
        if (tid == 0) s_cnt = 0;
        __syncthreads();
        int c = 0;
        if (useLds) for (int i = tid; i < n; i += blockDim.x) c += (s_vals[i] > mid) ? 1 : 0;
        else        for (int i = tid; i < n; i += blockDim.x) c += (cb[i].v  > mid) ? 1 : 0;
        #pragma unroll
        for (int o = 32; o >= 1; o >>= 1) c += __shfl_down(c, o);
        if ((tid & 63) == 0) atomicAdd(&s_cnt, c);
        __syncthreads();
        int cm = s_cnt;
        __syncthreads();
        if (cm == KKEEP) { if (tid == 0) { s_tau = mid; s_exact = 1; } break; }
        if (cm > KKEEP) lo = mid; else hi = mid;
    }
    __syncthreads();

    const int   exact = s_exact;
    const float tau   = exact ? s_tau : hi;

    for (int i = tid; i < KKEEP; i += blockDim.x) { s_A[i].v = 0.f; s_A[i].idx = 0u; }
    if (tid == 0) { s_nA = 0; s_nT = 0; }
    __syncthreads();

    for (int i = tid; i < n; i += blockDim.x) {
        float v = cb[i].v;
        if (v > tau) {
            int p = atomicAdd(&s_nA, 1);
            if (p < KKEEP) s_A[p] = cb[i];
        } else if (!exact && v == tau) {
            int p = atomicAdd(&s_nT, 1);
            if (p < 256) s_T[p] = cb[i].idx;
        }
    }
    __syncthreads();
    if (tid == 0) {
        int nA = s_nA; if (nA > KKEEP) nA = KKEEP;
        int need = KKEEP - nA;
        int nT = s_nT; if (nT > 256) nT = 256;
        for (int r = 0; r < need && r < nT; ++r) {
            unsigned best = 0xffffffffu; int bj = -1;
            for (int j = 0; j < nT; ++j) if (s_T[j] < best) { best = s_T[j]; bj = j; }
            Cand c; c.v = tau; c.idx = best;
            s_A[nA + r] = c;
            if (bj >= 0) s_T[bj] = 0xffffffffu;
        }
    }
    __syncthreads();
    for (int i = tid; i < KKEEP; i += blockDim.x) sel[b * KKEEP + i] = s_A[i];
}

// ---------------------------------------------------------------------------
// recon[b,t] = sum_e val_e * atoms[a_e, t - t0_e]  (gather, deterministic)
// ---------------------------------------------------------------------------
__global__ void recon_kernel(const float* __restrict__ atoms, const Cand* __restrict__ sel,
                             float* __restrict__ out) {
    __shared__ float          s_v[KKEEP];
    __shared__ unsigned short s_a[KKEEP];
    __shared__ unsigned short s_t[KKEEP];
    const int b = blockIdx.x >> 7;
    const int t = ((blockIdx.x & 127) << 8) + threadIdx.x;
    for (int i = threadIdx.x; i < KKEEP; i += blockDim.x) {
        Cand c = sel[b * KKEEP + i];
        s_v[i] = c.v;
        s_a[i] = (unsigned short)(c.idx >> 15);
        s_t[i] = (unsigned short)(c.idx & (NS - 1));
    }
    __syncthreads();
    float acc = 0.f;
    for (int e = 0; e < KKEEP; ++e) {
        int d = t - (int)s_t[e];
        if ((unsigned)d < (unsigned)AL)
            acc += s_v[e] * atoms[(size_t)s_a[e] * AL + d];
    }
    out[b * NS + t] = acc;
}

extern "C" void kernel_launch(void* const* d_in, const int* in_sizes, int n_in,
                              void* d_out, int out_size, void* d_ws, size_t ws_size,
                              hipStream_t stream) {
    const float* x     = (const float*)d_in[0];   // (2,1,32768)
    const float* atoms = (const float*)d_in[1];   // (1,1024,2048)
    float* out = (float*)d_out;                   // (2,1,32768)

    float*          hdr     = (float*)d_ws;
    unsigned*       candCnt = (unsigned*)((char*)d_ws + 16);
    Cand*           sel     = (Cand*)((char*)d_ws + 64);
    unsigned short* ab16    = (unsigned short*)((char*)d_ws + 65536);
    const size_t    candOff = 65536 + (size_t)NA * AL * 2;   // 4,259,840
    Cand*           cand    = (Cand*)((char*)d_ws + candOff);

    unsigned cap = CAPC;
    if (ws_size > candOff + 2 * sizeof(Cand) * 1024) {
        size_t fit = (ws_size - candOff) / (2 * sizeof(Cand));
        if (fit < cap) cap = (unsigned)fit;
    } else {
        cap = 1024;
    }

    hipMemsetAsync(d_ws, 0, 256, stream);  // hdr + counters
    sums_kernel     <<<512, 256, 0, stream>>>(x, atoms, hdr);
    cvt_atoms_kernel<<<(NA * AL) / (256 * 4), 256, 0, stream>>>(atoms, ab16);
    fm_kernel       <<<2 * (NA / 128) * (NS / 256), 256, 0, stream>>>(x, ab16, hdr, candCnt, cand, cap);
    refine_kernel   <<<2048, 256, 0, stream>>>(x, atoms, candCnt, cand, cap);
    select_kernel   <<<2, 1024, 0, stream>>>(candCnt, cand, sel, cap);
    recon_kernel    <<<256, 256, 0, stream>>>(atoms, sel, out);
}

// Round 6
// 530.196 us; speedup vs baseline: 18.3356x; 1.0901x over previous
//
#include <hip/hip_runtime.h>
#include <hip/hip_bf16.h>

#define NS    32768    // samples
#define NA    1024     // atoms
#define AL    2048     // atom length
#define KKEEP 1024     // top-k
#define CAPC  (512*1024)

struct Cand { float v; unsigned idx; };

typedef short  short8  __attribute__((ext_vector_type(8)));
typedef short  short4v __attribute__((ext_vector_type(4)));
typedef float  f32x4   __attribute__((ext_vector_type(4)));

// ---------------------------------------------------------------------------
// ws layout (bytes):
//   0       : float hdr[3]  { sumsq x[b=0], sumsq x[b=1], sumsq atoms }
//   16      : unsigned candCnt[2]
//   64      : Cand sel[2][KKEEP]                  (16 KB)
//   65536   : unsigned short ab16[1024*2048]      (4 MB, bf16 atoms)
//   4259840 : Cand cand[2][cap]
// ---------------------------------------------------------------------------

__device__ inline unsigned short f2bf(float f) {
    union { float f; unsigned u; } v; v.f = f;
    unsigned r = v.u + 0x7fffu + ((v.u >> 16) & 1u);   // round-to-nearest-even
    return (unsigned short)(r >> 16);
}

__global__ void sums_kernel(const float* __restrict__ x, const float* __restrict__ atoms,
                            float* __restrict__ hdr) {
    const long total = 2L*NS + (long)NA*AL;
    float sx0 = 0.f, sx1 = 0.f, sa = 0.f;
    for (long i = (long)blockIdx.x*blockDim.x + threadIdx.x; i < total;
         i += (long)gridDim.x*blockDim.x) {
        if (i < NS)        { float v = x[i];            sx0 += v*v; }
        else if (i < 2*NS) { float v = x[i];            sx1 += v*v; }
        else               { float v = atoms[i - 2*NS]; sa  += v*v; }
    }
    #pragma unroll
    for (int o = 32; o >= 1; o >>= 1) {
        sx0 += __shfl_down(sx0, o);
        sx1 += __shfl_down(sx1, o);
        sa  += __shfl_down(sa , o);
    }
    if ((threadIdx.x & 63) == 0) {
        if (sx0 != 0.f) atomicAdd(&hdr[0], sx0);
        if (sx1 != 0.f) atomicAdd(&hdr[1], sx1);
        if (sa  != 0.f) atomicAdd(&hdr[2], sa);
    }
}

__global__ void cvt_atoms_kernel(const float* __restrict__ atoms,
                                 unsigned short* __restrict__ ab16) {
    int i = (blockIdx.x * 256 + threadIdx.x) * 4;     // grid covers 2M elems
    float4 f = *(const float4*)(atoms + i);
    ushort4 o;
    o.x = f2bf(f.x); o.y = f2bf(f.y); o.z = f2bf(f.z); o.w = f2bf(f.w);
    *(ushort4*)(ab16 + i) = o;
}

// ---------------------------------------------------------------------------
// MFMA fm kernel, 2-phase pipelined, block tile 128 atoms x 128 t,
// 4 waves (2m x 2n), wave tile 64x64: acc[4][4] = 64 AGPR.  Total regs
// ~152/wave (88 VGPR + 64 AGPR, unified file) -> 3 waves/SIMD; LDS ~50 KB
// -> 3 blocks/CU = 12 waves/CU (round 5 was capped at 2/SIMD by acc[4][8]).
//
// B operand (x Toeplitz) from REVERSED bf16 x-window in LDS:
// frag elem j = xr[R+j], R(ni,S) = Rbase - 16*ni + 32*S,
// Rbase = 127 - wn*64 - ln + 8*g, xr[p] = x[t0+127-p].
// Rolling identity: frag(ni,S+1) = frag(ni-2,S) -> only ni=0,1 fresh/k-step.
// 4 shifted copies (p = (R+3)&~3, m = p-R in 0..3), copy stride 4384 B
// (== 32 mod 128): each B-frag = two 8B-aligned ds_read_b64, and the 16
// lanes of a group hit 16 distinct 8B slots -> conflict-free.
// A tile staged via global_load_lds(16B), XOR swizzle folded into the
// per-lane GLOBAL source address (LDS dest linear).  K-chunk order rotated
// per block ((c+rot)&31) to de-convoy L2.
// ---------------------------------------------------------------------------
#define XRW      2175      // reversed-window elements: [t0-2047 .. t0+127]
#define XRSTRIDE 2192      // elems per copy (4384 B: mult of 8, == 32 mod 128)
#define XRB      4384
#define NCPY     4
#define SA_BUF   16384     // bytes per A buffer (128 rows x 8 blk x 16B)

__device__ inline void gload_lds16(const unsigned short* g, unsigned char* lds) {
    __builtin_amdgcn_global_load_lds((const __attribute__((address_space(1))) void*)g,
                                     (__attribute__((address_space(3))) void*)lds,
                                     16, 0, 0);
}

__global__ __launch_bounds__(256, 3)
void fm_kernel(const float* __restrict__ x, const unsigned short* __restrict__ ab16,
               const float* __restrict__ hdr, unsigned* __restrict__ candCnt,
               Cand* __restrict__ cand, unsigned cap)
{
    __shared__ __align__(16) unsigned char  sA[2 * SA_BUF];
    __shared__ __align__(16) unsigned short sXR[NCPY * XRSTRIDE];

    const int bid = blockIdx.x;
    const int b   = bid >> 11;          // grid = 2 * 8 * 256
    const int rem = bid & 2047;
    const int a0  = (rem >> 8) * 128;
    const int t0  = (rem & 255) * 128;

    const int tid  = threadIdx.x;
    const int lane = tid & 63;
    const int wid  = tid >> 6;
    const int wm   = wid >> 1;          // 0..1 (m 64-block)
    const int wn   = wid & 1;           // 0..1 (n 64-block)
    const int g    = lane >> 4;         // k-group 0..3
    const int ln   = lane & 15;

    const int rot = (bid * 5) & 31;     // per-block K-chunk rotation

    const float* __restrict__ xb = x + b * NS;

    // ---- stage reversed x window as bf16, 4 shifted copies ----
    for (int ti = tid; ti < XRW; ti += 256) {
        int t = t0 - 2047 + ti;
        float f = (t >= 0) ? xb[t] : 0.f;
        unsigned short h = f2bf(f);
        int p0 = 2174 - ti;                       // xr[p] = x[t0+127-p]
        #pragma unroll
        for (int m = 0; m < NCPY; ++m) sXR[m * XRSTRIDE + p0 + m] = h;
    }

    // stage A chunk `ck` (64 k-elems) into buffer `bf`
    #define STAGE(bf, ck) do {                                                   \
        int kcs = (ck) * 64;                                                     \
        _Pragma("unroll")                                                        \
        for (int it = 0; it < 4; ++it) {                                         \
            int slot = (wid * 4 + it) * 64 + lane;                               \
            int row  = slot >> 3;                                                \
            int blk  = slot & 7;                                                 \
            const unsigned short* gsrc =                                         \
                ab16 + (size_t)(a0 + row) * AL + kcs + ((blk ^ (row & 7)) << 3); \
            gload_lds16(gsrc, sA + (bf) * SA_BUF + (size_t)(wid * 4 + it) * 1024); \
        }                                                                        \
    } while (0)

    f32x4 acc[4][4];
    #pragma unroll
    for (int i = 0; i < 4; ++i)
        #pragma unroll
        for (int j = 0; j < 4; ++j) acc[i][j] = (f32x4)0.0f;

    // lane-constant base: R(ni,S) = Rbase - 16*ni + 32*S
    const int Rbase = 127 - wn * 64 - ln + 8 * g;
    const unsigned char* xrb = (const unsigned char*)sXR;

    // loadB(R): p = (R+3)&~3 (8B-aligned slot), copy m = p-R, two b64 reads
    #define LOADB(Rv, dst) do {                                                 \
        int p_ = ((Rv) + 3) & ~3;                                               \
        const unsigned char* a_ =                                               \
            xrb + (unsigned)(p_ - (Rv)) * XRB + (unsigned)p_ * 2u;              \
        short4v lo_ = *(const short4v*)a_;                                      \
        short4v hi_ = *(const short4v*)(a_ + 8);                                \
        dst = __builtin_shufflevector(lo_, hi_, 0, 1, 2, 3, 4, 5, 6, 7);        \
    } while (0)

    short8 b0, b1, b2, b3;

    #define LOADB4(Sv) do {                        \
        LOADB(Rbase      + 32 * (Sv), b0);         \
        LOADB(Rbase - 16 + 32 * (Sv), b1);         \
        LOADB(Rbase - 32 + 32 * (Sv), b2);         \
        LOADB(Rbase - 48 + 32 * (Sv), b3);         \
    } while (0)

    // frag(ni,S+1) = frag(ni-2,S): shift chain + 2 fresh
    #define ROLLB(Sv) do {                         \
        b3 = b1; b2 = b0;                          \
        LOADB(Rbase      + 32 * (Sv), b0);         \
        LOADB(Rbase - 16 + 32 * (Sv), b1);         \
    } while (0)

    #define MFMAS(mi) do {                                                                  \
        acc[mi][0] = __builtin_amdgcn_mfma_f32_16x16x32_bf16(af[mi], b0, acc[mi][0],0,0,0); \
        acc[mi][1] = __builtin_amdgcn_mfma_f32_16x16x32_bf16(af[mi], b1, acc[mi][1],0,0,0); \
        acc[mi][2] = __builtin_amdgcn_mfma_f32_16x16x32_bf16(af[mi], b2, acc[mi][2],0,0,0); \
        acc[mi][3] = __builtin_amdgcn_mfma_f32_16x16x32_bf16(af[mi], b3, acc[mi][3],0,0,0); \
    } while (0)

    STAGE(0, rot);            // prologue stage
    __syncthreads();          // xr copies + first A chunk visible

    LOADB4(rot * 2);

    int cur = 0;
    for (int c = 0; c < 32; ++c) {
        const int chunk  = (c + rot) & 31;
        const int nchunk = (c + 1 + rot) & 31;
        if (c + 1 < 32) STAGE(cur ^ 1, nchunk);     // prefetch next chunk

        #pragma unroll
        for (int s = 0; s < 2; ++s) {
            short8 af[4];
            #pragma unroll
            for (int mi = 0; mi < 4; ++mi) {
                int row = wm * 64 + mi * 16 + ln;
                int off = cur * SA_BUF + row * 128 + (((s * 4 + g) ^ (row & 7)) << 4);
                af[mi] = *(const short8*)(sA + off);
            }
            MFMAS(0); MFMAS(1); MFMAS(2); MFMAS(3);

            if (s == 0) {
                ROLLB(chunk * 2 + 1);
            } else {
                if (nchunk == 0) { LOADB4(0); }     // wrap (or dead tail)
                else             { ROLLB(nchunk * 2); }
            }
        }
        __syncthreads();      // drains my gloads (vmcnt0) + everyone's ds reads
        cur ^= 1;
    }
    #undef LOADB
    #undef LOADB4
    #undef ROLLB
    #undef MFMAS
    #undef STAGE

    // ---- threshold + candidate append ----
    const float sig = sqrtf((hdr[2] * (1.0f / (float)NA)) * (hdr[b] * (1.0f / (float)NS)));
    const float T0  = 3.35f * sig;   // cutoff ~4sigma; bf16 noise ~0.006sigma

    #pragma unroll
    for (int mi = 0; mi < 4; ++mi) {
        #pragma unroll
        for (int ni = 0; ni < 4; ++ni) {
            #pragma unroll
            for (int r = 0; r < 4; ++r) {
                float v = acc[mi][ni][r];
                if (v > T0) {
                    unsigned a = (unsigned)(a0 + wm * 64 + mi * 16 + g * 4 + r);
                    unsigned t = (unsigned)(t0 + wn * 64 + ni * 16 + ln);
                    unsigned idx = (a << 15) | t;
                    unsigned pos = atomicAdd(&candCnt[b], 1u);
                    if (pos < cap) {
                        Cand cc; cc.v = v; cc.idx = idx;
                        cand[(size_t)b * cap + pos] = cc;
                    }
                }
            }
        }
    }
}

// ---------------------------------------------------------------------------
// Exact fp64 re-evaluation of each candidate (selection authority).
// ---------------------------------------------------------------------------
__global__ void refine_kernel(const float* __restrict__ x, const float* __restrict__ atoms,
                              const unsigned* __restrict__ candCnt, Cand* __restrict__ cand,
                              unsigned cap) {
    const int lane = threadIdx.x & 63;
    const int wid  = (int)((blockIdx.x * blockDim.x + threadIdx.x) >> 6);
    const int nw   = (int)((gridDim.x * blockDim.x) >> 6);
    const int n0 = (int)min(candCnt[0], cap);
    const int n1 = (int)min(candCnt[1], cap);
    const int total = n0 + n1;
    for (int c = wid; c < total; c += nw) {
        const int b = (c < n0) ? 0 : 1;
        const size_t ci = (c < n0) ? (size_t)c : ((size_t)cap + (size_t)(c - n0));
        const unsigned idx = cand[ci].idx;
        const int a = (int)(idx >> 15);
        const int t = (int)(idx & (NS - 1));
        const float* __restrict__ ar = atoms + (size_t)a * AL;
        const float* __restrict__ xr = x + b * NS;
        double s = 0.0;
        for (int k = lane; k < AL; k += 64) {
            int xi = t - k;
            if (xi >= 0) s += (double)ar[k] * (double)xr[xi];
        }
        #pragma unroll
        for (int o = 32; o >= 1; o >>= 1) s += __shfl_down(s, o);
        if (lane == 0) cand[ci].v = (float)s;
    }
}

// ---------------------------------------------------------------------------
// Exact top-KKEEP among candidates (binary search on threshold; ties by
// ascending flat index = jax.lax.top_k semantics). One block per batch.
// Candidate values cached in LDS for the search sweeps.
// ---------------------------------------------------------------------------
#define SELCAP 16384

__global__ void select_kernel(const unsigned* __restrict__ candCnt,
                              const Cand* __restrict__ cand, Cand* __restrict__ sel,
                              unsigned cap) {
    __shared__ float    s_vals[SELCAP];
    __shared__ float    s_red[16];
    __shared__ int      s_cnt;
    __shared__ int      s_nA;
    __shared__ int      s_nT;
    __shared__ int      s_exact;
    __shared__ float    s_tau;
    __shared__ Cand     s_A[KKEEP];
    __shared__ unsigned s_T[256];

    const int b = blockIdx.x;
    const Cand* __restrict__ cb = cand + (size_t)b * cap;
    const int n   = (int)min(candCnt[b], cap);
    const int tid = threadIdx.x;

    if (n <= KKEEP) {   // statistically unreachable; safe fallback
        for (int i = tid; i < KKEEP; i += blockDim.x) {
            Cand z; z.v = 0.f; z.idx = 0u;
            sel[b * KKEEP + i] = (i < n) ? cb[i] : z;
        }
        return;
    }

    const bool useLds = (n <= SELCAP);
    if (useLds)
        for (int i = tid; i < n; i += blockDim.x) s_vals[i] = cb[i].v;

    float m = 0.f;
    if (useLds) { __syncthreads();
        for (int i = tid; i < n; i += blockDim.x) m = fmaxf(m, s_vals[i]);
    } else {
        for (int i = tid; i < n; i += blockDim.x) m = fmaxf(m, cb[i].v);
    }
    #pragma unroll
    for (int o = 32; o >= 1; o >>= 1) m = fmaxf(m, __shfl_down(m, o));
    if ((tid & 63) == 0) s_red[tid >> 6] = m;
    if (tid == 0) s_exact = 0;
    __syncthreads();
    float hi;
    {
        float mm = 0.f;
        #pragma unroll
        for (int w = 0; w < 16; ++w) mm = fmaxf(mm, s_red[w]);
        hi = mm;
    }
    float lo = 0.f;
    for (int iter = 0; iter < 64; ++iter) {
        float mid = 0.5f * (lo + hi);
        if (!(mid > lo && mid < hi)) break;
        if (tid == 0) s_cnt = 0;
        __syncthreads();
        int c = 0;
        if (useLds) for (int i = tid; i < n; i += blockDim.x) c += (s_vals[i] > mid) ? 1 : 0;
        else        for (int i = tid; i < n; i += blockDim.x) c += (cb[i].v  > mid) ? 1 : 0;
        #pragma unroll
        for (int o = 32; o >= 1; o >>= 1) c += __shfl_down(c, o);
        if ((tid & 63) == 0) atomicAdd(&s_cnt, c);
        __syncthreads();
        int cm = s_cnt;
        __syncthreads();
        if (cm == KKEEP) { if (tid == 0) { s_tau = mid; s_exact = 1; } break; }
        if (cm > KKEEP) lo = mid; else hi = mid;
    }
    __syncthreads();

    const int   exact = s_exact;
    const float tau   = exact ? s_tau : hi;

    for (int i = tid; i < KKEEP; i += blockDim.x) { s_A[i].v = 0.f; s_A[i].idx = 0u; }
    if (tid == 0) { s_nA = 0; s_nT = 0; }
    __syncthreads();

    for (int i = tid; i < n; i += blockDim.x) {
        float v = cb[i].v;
        if (v > tau) {
            int p = atomicAdd(&s_nA, 1);
            if (p < KKEEP) s_A[p] = cb[i];
        } else if (!exact && v == tau) {
            int p = atomicAdd(&s_nT, 1);
            if (p < 256) s_T[p] = cb[i].idx;
        }
    }
    __syncthreads();
    if (tid == 0) {
        int nA = s_nA; if (nA > KKEEP) nA = KKEEP;
        int need = KKEEP - nA;
        int nT = s_nT; if (nT > 256) nT = 256;
        for (int r = 0; r < need && r < nT; ++r) {
            unsigned best = 0xffffffffu; int bj = -1;
            for (int j = 0; j < nT; ++j) if (s_T[j] < best) { best = s_T[j]; bj = j; }
            Cand c; c.v = tau; c.idx = best;
            s_A[nA + r] = c;
            if (bj >= 0) s_T[bj] = 0xffffffffu;
        }
    }
    __syncthreads();
    for (int i = tid; i < KKEEP; i += blockDim.x) sel[b * KKEEP + i] = s_A[i];
}

// ---------------------------------------------------------------------------
// recon[b,t] = sum_e val_e * atoms[a_e, t - t0_e]  (gather, deterministic
// within threshold).  Per-segment filter: only ~72 of 1024 entries touch a
// 256-sample segment -> compact LDS list first, then the FMA loop.
// ---------------------------------------------------------------------------
__global__ void recon_kernel(const float* __restrict__ atoms, const Cand* __restrict__ sel,
                             float* __restrict__ out) {
    __shared__ float s_cv[KKEEP];
    __shared__ int   s_ca[KKEEP];
    __shared__ int   s_ct[KKEEP];
    __shared__ int   s_n;
    const int b    = blockIdx.x >> 7;                    // 128 blocks per batch
    const int tseg = (blockIdx.x & 127) << 8;
    const int t    = tseg + threadIdx.x;
    if (threadIdx.x == 0) s_n = 0;
    __syncthreads();
    for (int i = threadIdx.x; i < KKEEP; i += blockDim.x) {
        Cand c = sel[b * KKEEP + i];
        int t0e = (int)(c.idx & (NS - 1));
        // eligible iff [t0e, t0e+AL-1] intersects [tseg, tseg+255]
        if (c.v != 0.f && t0e <= tseg + 255 && t0e + (AL - 1) >= tseg) {
            int p = atomicAdd(&s_n, 1);
            s_cv[p] = c.v;
            s_ca[p] = (int)(c.idx >> 15);
            s_ct[p] = t0e;
        }
    }
    __syncthreads();
    const int n = s_n;
    float acc = 0.f;
    for (int e = 0; e < n; ++e) {
        int d = t - s_ct[e];
        if ((unsigned)d < (unsigned)AL)
            acc += s_cv[e] * atoms[(size_t)s_ca[e] * AL + d];
    }
    out[b * NS + t] = acc;
}

extern "C" void kernel_launch(void* const* d_in, const int* in_sizes, int n_in,
                              void* d_out, int out_size, void* d_ws, size_t ws_size,
                              hipStream_t stream) {
    const float* x     = (const float*)d_in[0];   // (2,1,32768)
    const float* atoms = (const float*)d_in[1];   // (1,1024,2048)
    float* out = (float*)d_out;                   // (2,1,32768)

    float*          hdr     = (float*)d_ws;
    unsigned*       candCnt = (unsigned*)((char*)d_ws + 16);
    Cand*           sel     = (Cand*)((char*)d_ws + 64);
    unsigned short* ab16    = (unsigned short*)((char*)d_ws + 65536);
    const size_t    candOff = 65536 + (size_t)NA * AL * 2;   // 4,259,840
    Cand*           cand    = (Cand*)((char*)d_ws + candOff);

    unsigned cap = CAPC;
    if (ws_size > candOff + 2 * sizeof(Cand) * 1024) {
        size_t fit = (ws_size - candOff) / (2 * sizeof(Cand));
        if (fit < cap) cap = (unsigned)fit;
    } else {
        cap = 1024;
    }

    hipMemsetAsync(d_ws, 0, 256, stream);  // hdr + counters
    sums_kernel     <<<512, 256, 0, stream>>>(x, atoms, hdr);
    cvt_atoms_kernel<<<(NA * AL) / (256 * 4), 256, 0, stream>>>(atoms, ab16);
    fm_kernel       <<<2 * (NA / 128) * (NS / 128), 256, 0, stream>>>(x, ab16, hdr, candCnt, cand, cap);
    refine_kernel   <<<2048, 256, 0, stream>>>(x, atoms, candCnt, cand, cap);
    select_kernel   <<<2, 1024, 0, stream>>>(candCnt, cand, sel, cap);
    recon_kernel    <<<256, 256, 0, stream>>>(atoms, sel, out);
}

// Round 7
// 517.395 us; speedup vs baseline: 18.7892x; 1.0247x over previous
//
#include <hip/hip_runtime.h>
#include <hip/hip_bf16.h>

#define NS    32768    // samples
#define NA    1024     // atoms
#define AL    2048     // atom length
#define KKEEP 1024     // top-k
#define CAPC  (512*1024)

struct Cand { float v; unsigned idx; };

typedef short  short8  __attribute__((ext_vector_type(8)));
typedef short  short4v __attribute__((ext_vector_type(4)));
typedef float  f32x4   __attribute__((ext_vector_type(4)));

// ---------------------------------------------------------------------------
// ws layout (bytes):
//   0       : float hdr[3]  { sumsq x[b=0], sumsq x[b=1], sumsq atoms }
//   16      : unsigned candCnt[2]
//   64      : Cand sel[2][KKEEP]                  (16 KB)
//   65536   : unsigned short ab16[1024*2048]      (4 MB, bf16 atoms)
//   4259840 : Cand cand[2][cap]
// ---------------------------------------------------------------------------

__device__ inline unsigned short f2bf(float f) {
    union { float f; unsigned u; } v; v.f = f;
    unsigned r = v.u + 0x7fffu + ((v.u >> 16) & 1u);   // round-to-nearest-even
    return (unsigned short)(r >> 16);
}

__global__ void sums_kernel(const float* __restrict__ x, const float* __restrict__ atoms,
                            float* __restrict__ hdr) {
    const long total = 2L*NS + (long)NA*AL;
    float sx0 = 0.f, sx1 = 0.f, sa = 0.f;
    for (long i = (long)blockIdx.x*blockDim.x + threadIdx.x; i < total;
         i += (long)gridDim.x*blockDim.x) {
        if (i < NS)        { float v = x[i];            sx0 += v*v; }
        else if (i < 2*NS) { float v = x[i];            sx1 += v*v; }
        else               { float v = atoms[i - 2*NS]; sa  += v*v; }
    }
    #pragma unroll
    for (int o = 32; o >= 1; o >>= 1) {
        sx0 += __shfl_down(sx0, o);
        sx1 += __shfl_down(sx1, o);
        sa  += __shfl_down(sa , o);
    }
    if ((threadIdx.x & 63) == 0) {
        if (sx0 != 0.f) atomicAdd(&hdr[0], sx0);
        if (sx1 != 0.f) atomicAdd(&hdr[1], sx1);
        if (sa  != 0.f) atomicAdd(&hdr[2], sa);
    }
}

__global__ void cvt_atoms_kernel(const float* __restrict__ atoms,
                                 unsigned short* __restrict__ ab16) {
    int i = (blockIdx.x * 256 + threadIdx.x) * 4;     // grid covers 2M elems
    float4 f = *(const float4*)(atoms + i);
    ushort4 o;
    o.x = f2bf(f.x); o.y = f2bf(f.y); o.z = f2bf(f.z); o.w = f2bf(f.w);
    *(ushort4*)(ab16 + i) = o;
}

// ---------------------------------------------------------------------------
// MFMA fm kernel, counted-vmcnt 2-deep pipeline (T4), raw barriers, setprio.
//
//   prologue: STAGE(b0, c0); STAGE(b1, c1)            (8 loads in flight)
//   iter c :  s_waitcnt vmcnt(4)   <- chunk c landed (staged 2 iters ago,
//                                     ~1.5 iterations of flight time)
//             s_barrier
//             compute chunk c from buf[c&1]  (MFMAs wrapped in setprio 1/0)
//             s_barrier
//             STAGE(buf[c&1], chunk c+2)     (never vmcnt(0) in the loop)
//
// B operand (x Toeplitz) from REVERSED bf16 x-window in LDS:
// frag elem j = xr[R+j], R(ni,S) = Rbase - 16*ni + 32*S,
// Rbase = 127 - wn*64 - ln + 8*g, xr[p] = x[t0+127-p].
// Rolling identity: frag(ni,S+1) = frag(ni-2,S) -> only ni=0,1 fresh/k-step.
// 4 shifted copies (p=(R+3)&~3, m=p-R in 0..3, stride 4384 B == 32 mod 128):
// each B-frag = two 8B-aligned ds_read_b64.
// A tile staged via global_load_lds(16B), XOR swizzle folded into the
// per-lane GLOBAL source address (LDS dest linear); read back with
// blk' = blk ^ (row&7) -> conflict-free ds_read_b128.
// K-chunk order rotated per block ((c+rot)&31) to de-convoy L2.
// ---------------------------------------------------------------------------
#define XRW      2175      // reversed-window elements: [t0-2047 .. t0+127]
#define XRSTRIDE 2192      // elems per copy (4384 B: mult of 8, == 32 mod 128)
#define XRB      4384
#define NCPY     4
#define SA_BUF   16384     // bytes per A buffer (128 rows x 8 blk x 16B)

__device__ inline void gload_lds16(const unsigned short* g, unsigned char* lds) {
    __builtin_amdgcn_global_load_lds((const __attribute__((address_space(1))) void*)g,
                                     (__attribute__((address_space(3))) void*)lds,
                                     16, 0, 0);
}

__global__ __launch_bounds__(256, 3)
void fm_kernel(const float* __restrict__ x, const unsigned short* __restrict__ ab16,
               const float* __restrict__ hdr, unsigned* __restrict__ candCnt,
               Cand* __restrict__ cand, unsigned cap)
{
    __shared__ __align__(16) unsigned char  sA[2 * SA_BUF];
    __shared__ __align__(16) unsigned short sXR[NCPY * XRSTRIDE];

    const int bid = blockIdx.x;
    const int b   = bid >> 11;          // grid = 2 * 8 * 256
    const int rem = bid & 2047;
    const int a0  = (rem >> 8) * 128;
    const int t0  = (rem & 255) * 128;

    const int tid  = threadIdx.x;
    const int lane = tid & 63;
    const int wid  = tid >> 6;
    const int wm   = wid >> 1;          // 0..1 (m 64-block)
    const int wn   = wid & 1;           // 0..1 (n 64-block)
    const int g    = lane >> 4;         // k-group 0..3
    const int ln   = lane & 15;

    const int rot = (bid * 5) & 31;     // per-block K-chunk rotation

    const float* __restrict__ xb = x + b * NS;

    // ---- stage reversed x window as bf16, 4 shifted copies ----
    for (int ti = tid; ti < XRW; ti += 256) {
        int t = t0 - 2047 + ti;
        float f = (t >= 0) ? xb[t] : 0.f;
        unsigned short h = f2bf(f);
        int p0 = 2174 - ti;                       // xr[p] = x[t0+127-p]
        #pragma unroll
        for (int m = 0; m < NCPY; ++m) sXR[m * XRSTRIDE + p0 + m] = h;
    }

    // stage A chunk `ck` (64 k-elems) into buffer `bf`
    #define STAGE(bf, ck) do {                                                   \
        int kcs = (ck) * 64;                                                     \
        _Pragma("unroll")                                                        \
        for (int it = 0; it < 4; ++it) {                                         \
            int slot = (wid * 4 + it) * 64 + lane;                               \
            int row  = slot >> 3;                                                \
            int blk  = slot & 7;                                                 \
            const unsigned short* gsrc =                                         \
                ab16 + (size_t)(a0 + row) * AL + kcs + ((blk ^ (row & 7)) << 3); \
            gload_lds16(gsrc, sA + (bf) * SA_BUF + (size_t)(wid * 4 + it) * 1024); \
        }                                                                        \
    } while (0)

    f32x4 acc[4][4];
    #pragma unroll
    for (int i = 0; i < 4; ++i)
        #pragma unroll
        for (int j = 0; j < 4; ++j) acc[i][j] = (f32x4)0.0f;

    // lane-constant base: R(ni,S) = Rbase - 16*ni + 32*S
    const int Rbase = 127 - wn * 64 - ln + 8 * g;
    const unsigned char* xrb = (const unsigned char*)sXR;

    // lane-constant A-read offsets: row&7 == ln&7 (wm*64, mi*16 mults of 8)
    int rowoff[4];
    #pragma unroll
    for (int mi = 0; mi < 4; ++mi) rowoff[mi] = (wm * 64 + mi * 16 + ln) * 128;
    const int swz0 = ((0 * 4 + g) ^ (ln & 7)) << 4;   // s=0 swizzled blk byte-off
    const int swz1 = ((1 * 4 + g) ^ (ln & 7)) << 4;   // s=1

    // loadB(R): p = (R+3)&~3 (8B-aligned slot), copy m = p-R, two b64 reads
    #define LOADB(Rv, dst) do {                                                 \
        int p_ = ((Rv) + 3) & ~3;                                               \
        const unsigned char* a_ =                                               \
            xrb + (unsigned)(p_ - (Rv)) * XRB + (unsigned)p_ * 2u;              \
        short4v lo_ = *(const short4v*)a_;                                      \
        short4v hi_ = *(const short4v*)(a_ + 8);                                \
        dst = __builtin_shufflevector(lo_, hi_, 0, 1, 2, 3, 4, 5, 6, 7);        \
    } while (0)

    short8 b0, b1, b2, b3;

    #define LOADB4(Sv) do {                        \
        LOADB(Rbase      + 32 * (Sv), b0);         \
        LOADB(Rbase - 16 + 32 * (Sv), b1);         \
        LOADB(Rbase - 32 + 32 * (Sv), b2);         \
        LOADB(Rbase - 48 + 32 * (Sv), b3);         \
    } while (0)

    // frag(ni,S+1) = frag(ni-2,S): shift chain + 2 fresh
    #define ROLLB(Sv) do {                         \
        b3 = b1; b2 = b0;                          \
        LOADB(Rbase      + 32 * (Sv), b0);         \
        LOADB(Rbase - 16 + 32 * (Sv), b1);         \
    } while (0)

    #define MFMAS(mi) do {                                                                  \
        acc[mi][0] = __builtin_amdgcn_mfma_f32_16x16x32_bf16(af[mi], b0, acc[mi][0],0,0,0); \
        acc[mi][1] = __builtin_amdgcn_mfma_f32_16x16x32_bf16(af[mi], b1, acc[mi][1],0,0,0); \
        acc[mi][2] = __builtin_amdgcn_mfma_f32_16x16x32_bf16(af[mi], b2, acc[mi][2],0,0,0); \
        acc[mi][3] = __builtin_amdgcn_mfma_f32_16x16x32_bf16(af[mi], b3, acc[mi][3],0,0,0); \
    } while (0)

    __syncthreads();          // XR ds_writes drained + published

    LOADB4(rot * 2);          // B frags for first chunk

    STAGE(0, rot);                       // chunk c=0 (2-deep prologue)
    STAGE(1, (rot + 1) & 31);            // chunk c=1; 8 loads now in flight

    for (int c = 0; c < 32; ++c) {
        const int chunk  = (c + rot) & 31;
        const int nchunk = (c + 1 + rot) & 31;
        const int cur    = c & 1;

        // wait for chunk c's 4 loads (issued 2 iterations ago); newer 4 stay in flight
        asm volatile("s_waitcnt vmcnt(4)" ::: "memory");
        __builtin_amdgcn_sched_barrier(0);
        __builtin_amdgcn_s_barrier();
        __builtin_amdgcn_sched_barrier(0);

        #pragma unroll
        for (int s = 0; s < 2; ++s) {
            short8 af[4];
            const int soff = cur * SA_BUF + (s ? swz1 : swz0);
            #pragma unroll
            for (int mi = 0; mi < 4; ++mi)
                af[mi] = *(const short8*)(sA + soff + rowoff[mi]);

            __builtin_amdgcn_s_setprio(1);
            MFMAS(0); MFMAS(1); MFMAS(2); MFMAS(3);
            __builtin_amdgcn_s_setprio(0);

            if (s == 0) {
                ROLLB(chunk * 2 + 1);
            } else {
                if (nchunk == 0) { LOADB4(0); }     // wrap (or dead tail)
                else             { ROLLB(nchunk * 2); }
            }
        }

        // all waves done reading buf[cur] (their ds_read data already consumed
        // by the MFMAs above via compiler lgkmcnt waits)
        __builtin_amdgcn_sched_barrier(0);
        __builtin_amdgcn_s_barrier();
        __builtin_amdgcn_sched_barrier(0);

        // re-stage freed buffer with chunk c+2 (dead for c>=30; harmless)
        STAGE(cur, (c + 2 + rot) & 31);
    }
    #undef LOADB
    #undef LOADB4
    #undef ROLLB
    #undef MFMAS
    #undef STAGE

    // ---- threshold + candidate append ----
    const float sig = sqrtf((hdr[2] * (1.0f / (float)NA)) * (hdr[b] * (1.0f / (float)NS)));
    const float T0  = 3.35f * sig;   // cutoff ~4sigma; bf16 noise ~0.006sigma

    #pragma unroll
    for (int mi = 0; mi < 4; ++mi) {
        #pragma unroll
        for (int ni = 0; ni < 4; ++ni) {
            #pragma unroll
            for (int r = 0; r < 4; ++r) {
                float v = acc[mi][ni][r];
                if (v > T0) {
                    unsigned a = (unsigned)(a0 + wm * 64 + mi * 16 + g * 4 + r);
                    unsigned t = (unsigned)(t0 + wn * 64 + ni * 16 + ln);
                    unsigned idx = (a << 15) | t;
                    unsigned pos = atomicAdd(&candCnt[b], 1u);
                    if (pos < cap) {
                        Cand cc; cc.v = v; cc.idx = idx;
                        cand[(size_t)b * cap + pos] = cc;
                    }
                }
            }
        }
    }
}

// ---------------------------------------------------------------------------
// Exact fp64 re-evaluation of each candidate (selection authority).
// ---------------------------------------------------------------------------
__global__ void refine_kernel(const float* __restrict__ x, const float* __restrict__ atoms,
                              const unsigned* __restrict__ candCnt, Cand* __restrict__ cand,
                              unsigned cap) {
    const int lane = threadIdx.x & 63;
    const int wid  = (int)((blockIdx.x * blockDim.x + threadIdx.x) >> 6);
    const int nw   = (int)((gridDim.x * blockDim.x) >> 6);
    const int n0 = (int)min(candCnt[0], cap);
    const int n1 = (int)min(candCnt[1], cap);
    const int total = n0 + n1;
    for (int c = wid; c < total; c += nw) {
        const int b = (c < n0) ? 0 : 1;
        const size_t ci = (c < n0) ? (size_t)c : ((size_t)cap + (size_t)(c - n0));
        const unsigned idx = cand[ci].idx;
        const int a = (int)(idx >> 15);
        const int t = (int)(idx & (NS - 1));
        const float* __restrict__ ar = atoms + (size_t)a * AL;
        const float* __restrict__ xr = x + b * NS;
        double s = 0.0;
        for (int k = lane; k < AL; k += 64) {
            int xi = t - k;
            if (xi >= 0) s += (double)ar[k] * (double)xr[xi];
        }
        #pragma unroll
        for (int o = 32; o >= 1; o >>= 1) s += __shfl_down(s, o);
        if (lane == 0) cand[ci].v = (float)s;
    }
}

// ---------------------------------------------------------------------------
// Exact top-KKEEP among candidates (binary search on threshold; ties by
// ascending flat index = jax.lax.top_k semantics). One block per batch.
// Candidate values cached in LDS for the search sweeps.
// ---------------------------------------------------------------------------
#define SELCAP 16384

__global__ void select_kernel(const unsigned* __restrict__ candCnt,
                              const Cand* __restrict__ cand, Cand* __restrict__ sel,
                              unsigned cap) {
    __shared__ float    s_vals[SELCAP];
    __shared__ float    s_red[16];
    __shared__ int      s_cnt;
    __shared__ int      s_nA;
    __shared__ int      s_nT;
    __shared__ int      s_exact;
    __shared__ float    s_tau;
    __shared__ Cand     s_A[KKEEP];
    __shared__ unsigned s_T[256];

    const int b = blockIdx.x;
    const Cand* __restrict__ cb = cand + (size_t)b * cap;
    const int n   = (int)min(candCnt[b], cap);
    const int tid = threadIdx.x;

    if (n <= KKEEP) {   // statistically unreachable; safe fallback
        for (int i = tid; i < KKEEP; i += blockDim.x) {
            Cand z; z.v = 0.f; z.idx = 0u;
            sel[b * KKEEP + i] = (i < n) ? cb[i] : z;
        }
        return;
    }

    const bool useLds = (n <= SELCAP);
    if (useLds)
        for (int i = tid; i < n; i += blockDim.x) s_vals[i] = cb[i].v;

    float m = 0.f;
    if (useLds) { __syncthreads();
        for (int i = tid; i < n; i += blockDim.x) m = fmaxf(m, s_vals[i]);
    } else {
        for (int i = tid; i < n; i += blockDim.x) m = fmaxf(m, cb[i].v);
    }
    #pragma unroll
    for (int o = 32; o >= 1; o >>= 1) m = fmaxf(m, __shfl_down(m, o));
    if ((tid & 63) == 0) s_red[tid >> 6] = m;
    if (tid == 0) s_exact = 0;
    __syncthreads();
    float hi;
    {
        float mm = 0.f;
        #pragma unroll
        for (int w = 0; w < 16; ++w) mm = fmaxf(mm, s_red[w]);
        hi = mm;
    }
    float lo = 0.f;
    for (int iter = 0; iter < 64; ++iter) {
        float mid = 0.5f * (lo + hi);
        if (!(mid > lo && mid < hi)) break;
        if (tid == 0) s_cnt = 0;
        __syncthreads();
        int c = 0;
        if (useLds) for (int i = tid; i < n; i += blockDim.x) c += (s_vals[i] > mid) ? 1 : 0;
        else        for (int i = tid; i < n; i += blockDim.x) c += (cb[i].v  > mid) ? 1 : 0;
        #pragma unroll
        for (int o = 32; o >= 1; o >>= 1) c += __shfl_down(c, o);
        if ((tid & 63) == 0) atomicAdd(&s_cnt, c);
        __syncthreads();
        int cm = s_cnt;
        __syncthreads();
        if (cm == KKEEP) { if (tid == 0) { s_tau = mid; s_exact = 1; } break; }
        if (cm > KKEEP) lo = mid; else hi = mid;
    }
    __syncthreads();

    const int   exact = s_exact;
    const float tau   = exact ? s_tau : hi;

    for (int i = tid; i < KKEEP; i += blockDim.x) { s_A[i].v = 0.f; s_A[i].idx = 0u; }
    if (tid == 0) { s_nA = 0; s_nT = 0; }
    __syncthreads();

    for (int i = tid; i < n; i += blockDim.x) {
        float v = cb[i].v;
        if (v > tau) {
            int p = atomicAdd(&s_nA, 1);
            if (p < KKEEP) s_A[p] = cb[i];
        } else if (!exact && v == tau) {
            int p = atomicAdd(&s_nT, 1);
            if (p < 256) s_T[p] = cb[i].idx;
        }
    }
    __syncthreads();
    if (tid == 0) {
        int nA = s_nA; if (nA > KKEEP) nA = KKEEP;
        int need = KKEEP - nA;
        int nT = s_nT; if (nT > 256) nT = 256;
        for (int r = 0; r < need && r < nT; ++r) {
            unsigned best = 0xffffffffu; int bj = -1;
            for (int j = 0; j < nT; ++j) if (s_T[j] < best) { best = s_T[j]; bj = j; }
            Cand c; c.v = tau; c.idx = best;
            s_A[nA + r] = c;
            if (bj >= 0) s_T[bj] = 0xffffffffu;
        }
    }
    __syncthreads();
    for (int i = tid; i < KKEEP; i += blockDim.x) sel[b * KKEEP + i] = s_A[i];
}

// ---------------------------------------------------------------------------
// recon[b,t] = sum_e val_e * atoms[a_e, t - t0_e]  (gather, deterministic
// within threshold).  Per-segment filter: only ~72 of 1024 entries touch a
// 256-sample segment -> compact LDS list first, then the FMA loop.
// ---------------------------------------------------------------------------
__global__ void recon_kernel(const float* __restrict__ atoms, const Cand* __restrict__ sel,
                             float* __restrict__ out) {
    __shared__ float s_cv[KKEEP];
    __shared__ int   s_ca[KKEEP];
    __shared__ int   s_ct[KKEEP];
    __shared__ int   s_n;
    const int b    = blockIdx.x >> 7;                    // 128 blocks per batch
    const int tseg = (blockIdx.x & 127) << 8;
    const int t    = tseg + threadIdx.x;
    if (threadIdx.x == 0) s_n = 0;
    __syncthreads();
    for (int i = threadIdx.x; i < KKEEP; i += blockDim.x) {
        Cand c = sel[b * KKEEP + i];
        int t0e = (int)(c.idx & (NS - 1));
        // eligible iff [t0e, t0e+AL-1] intersects [tseg, tseg+255]
        if (c.v != 0.f && t0e <= tseg + 255 && t0e + (AL - 1) >= tseg) {
            int p = atomicAdd(&s_n, 1);
            s_cv[p] = c.v;
            s_ca[p] = (int)(c.idx >> 15);
            s_ct[p] = t0e;
        }
    }
    __syncthreads();
    const int n = s_n;
    float acc = 0.f;
    for (int e = 0; e < n; ++e) {
        int d = t - s_ct[e];
        if ((unsigned)d < (unsigned)AL)
            acc += s_cv[e] * atoms[(size_t)s_ca[e] * AL + d];
    }
    out[b * NS + t] = acc;
}

extern "C" void kernel_launch(void* const* d_in, const int* in_sizes, int n_in,
                              void* d_out, int out_size, void* d_ws, size_t ws_size,
                              hipStream_t stream) {
    const float* x     = (const float*)d_in[0];   // (2,1,32768)
    const float* atoms = (const float*)d_in[1];   // (1,1024,2048)
    float* out = (float*)d_out;                   // (2,1,32768)

    float*          hdr     = (float*)d_ws;
    unsigned*       candCnt = (unsigned*)((char*)d_ws + 16);
    Cand*           sel     = (Cand*)((char*)d_ws + 64);
    unsigned short* ab16    = (unsigned short*)((char*)d_ws + 65536);
    const size_t    candOff = 65536 + (size_t)NA * AL * 2;   // 4,259,840
    Cand*           cand    = (Cand*)((char*)d_ws + candOff);

    unsigned cap = CAPC;
    if (ws_size > candOff + 2 * sizeof(Cand) * 1024) {
        size_t fit = (ws_size - candOff) / (2 * sizeof(Cand));
        if (fit < cap) cap = (unsigned)fit;
    } else {
        cap = 1024;
    }

    hipMemsetAsync(d_ws, 0, 256, stream);  // hdr + counters
    sums_kernel     <<<512, 256, 0, stream>>>(x, atoms, hdr);
    cvt_atoms_kernel<<<(NA * AL) / (256 * 4), 256, 0, stream>>>(atoms, ab16);
    fm_kernel       <<<2 * (NA / 128) * (NS / 128), 256, 0, stream>>>(x, ab16, hdr, candCnt, cand, cap);
    refine_kernel   <<<2048, 256, 0, stream>>>(x, atoms, candCnt, cand, cap);
    select_kernel   <<<2, 1024, 0, stream>>>(candCnt, cand, sel, cap);
    recon_kernel    <<<256, 256, 0, stream>>>(atoms, sel, out);
}